// Round 1
// baseline (316.724 us; speedup 1.0000x reference)
//
#include <hip/hip_runtime.h>
#include <hip/hip_bf16.h>

// Causal attention, B=4 S=2048 E=1024 D=1024, fp32 in/out.
// Round 1: correctness-first MFMA pipeline.
//   cast(x,w)->bf16 -> GEMM_BT qkv -> [scores GEMM_BT causal-skip] -> softmax
//   -> transpose(V) -> GEMM_BT PV (K truncated per row tile) -> d_out fp32
// GEMM: 128x128 tile, BK=32, 4 waves of 4x4 mfma_f32_16x16x32_bf16.

typedef unsigned short u16;
typedef __attribute__((ext_vector_type(4))) u16   u16x4;
typedef __attribute__((ext_vector_type(8))) short short8;
typedef __attribute__((ext_vector_type(4))) float f32x4;
typedef __attribute__((ext_vector_type(4))) int   i32x4;

__device__ inline u16 f2b(float v) {
    __hip_bfloat16 b = __float2bfloat16(v);
    return *reinterpret_cast<u16*>(&b);
}

template <typename T> __device__ inline void store_elem(T* p, float v);
template <> __device__ inline void store_elem<float>(float* p, float v) { *p = v; }
template <> __device__ inline void store_elem<u16>(u16* p, float v)     { *p = f2b(v); }

// ---------------- fp32 -> bf16 cast, 4 elems/thread ----------------
__global__ __launch_bounds__(256) void cast_kernel(const float* __restrict__ src,
                                                   u16* __restrict__ dst, int n) {
    int idx = (blockIdx.x * 256 + threadIdx.x) * 4;
    if (idx >= n) return;
    float4 v = *(const float4*)(src + idx);
    u16x4 o;
    o.x = f2b(v.x); o.y = f2b(v.y); o.z = f2b(v.z); o.w = f2b(v.w);
    *(u16x4*)(dst + idx) = o;
}

// ---------------- BT-GEMM: C[M,N] = A[M,K] * B[N,K]^T (bf16 in, fp32 acc) ---
// MODE 0: plain. MODE 1: causal tile-skip (skip if n0 > m0). MODE 2: K
// truncated to m0+128 (PV with causal-zero P). All dims multiples of tile.
#define MT 128
#define NT 128
#define BK 32

template <int MODE, typename OutT>
__global__ __launch_bounds__(256) void gemm_bt(
    const u16* __restrict__ A, long long strideA, int lda,
    const u16* __restrict__ B, long long strideB, int ldb,
    OutT* __restrict__ C, long long strideC, int ldc,
    int M, int N, int K)
{
    const int m0 = blockIdx.y * MT;
    const int n0 = blockIdx.x * NT;
    if (MODE == 1 && n0 > m0) return;           // tile fully masked
    int Keff = K;
    if (MODE == 2) Keff = min(K, m0 + MT);      // P[m,t]=0 for t>m

    const u16* Ab = A + (long long)blockIdx.z * strideA;
    const u16* Bb = B + (long long)blockIdx.z * strideB;
    OutT*      Cb = C + (long long)blockIdx.z * strideC;

    __shared__ __align__(16) u16 As[MT * BK];
    __shared__ __align__(16) u16 Bs[NT * BK];

    const int tid  = threadIdx.x;
    const int lane = tid & 63;
    const int wave = tid >> 6;
    const int quad = lane >> 4;
    const int r16  = lane & 15;
    const int mw   = (wave >> 1) * 64;
    const int nw   = (wave & 1) * 64;

    f32x4 acc[4][4] = {};

    for (int kk = 0; kk < Keff; kk += BK) {
        __syncthreads();
        {   // stage 128x32 A and B tiles: 512 16B chunks each, 2 per thread
            int c0 = tid, c1 = tid + 256;
            int r0 = c0 >> 2, k0 = (c0 & 3) * 8;
            int r1 = c1 >> 2, k1 = (c1 & 3) * 8;
            *(i32x4*)&As[r0 * BK + k0] = *(const i32x4*)&Ab[(long long)(m0 + r0) * lda + kk + k0];
            *(i32x4*)&As[r1 * BK + k1] = *(const i32x4*)&Ab[(long long)(m0 + r1) * lda + kk + k1];
            *(i32x4*)&Bs[r0 * BK + k0] = *(const i32x4*)&Bb[(long long)(n0 + r0) * ldb + kk + k0];
            *(i32x4*)&Bs[r1 * BK + k1] = *(const i32x4*)&Bb[(long long)(n0 + r1) * ldb + kk + k1];
        }
        __syncthreads();

        short8 af[4], bf[4];
#pragma unroll
        for (int i = 0; i < 4; i++)
            af[i] = *(const short8*)&As[(mw + i * 16 + r16) * BK + quad * 8];
#pragma unroll
        for (int j = 0; j < 4; j++)
            bf[j] = *(const short8*)&Bs[(nw + j * 16 + r16) * BK + quad * 8];
#pragma unroll
        for (int i = 0; i < 4; i++)
#pragma unroll
            for (int j = 0; j < 4; j++)
                acc[i][j] = __builtin_amdgcn_mfma_f32_16x16x32_bf16(af[i], bf[j], acc[i][j], 0, 0, 0);
    }

    // epilogue: C/D layout col=lane&15, row=quad*4+reg
#pragma unroll
    for (int i = 0; i < 4; i++)
#pragma unroll
        for (int j = 0; j < 4; j++)
#pragma unroll
            for (int r = 0; r < 4; r++) {
                int m = m0 + mw + i * 16 + quad * 4 + r;
                int n = n0 + nw + j * 16 + r16;
                store_elem(&Cb[(long long)m * ldc + n], acc[i][j][r]);
            }
}

// ---------------- causal softmax over fp32 scores -> bf16 P -----------------
// one block per row; softmax(scores/32) over j<=i, zeros elsewhere.
__global__ __launch_bounds__(256) void softmax_kernel(const float* __restrict__ sc,
                                                      u16* __restrict__ P) {
    const int S = 2048;
    int row = blockIdx.x;            // b*S + i
    int i   = row & (S - 1);
    const float* srow = sc + (long long)row * S;
    u16*         prow = P  + (long long)row * S;
    int n = i + 1;

    __shared__ float red[8];
    float lmax = -1e30f;
    for (int j = threadIdx.x; j < n; j += 256) lmax = fmaxf(lmax, srow[j]);
    for (int o = 32; o > 0; o >>= 1) lmax = fmaxf(lmax, __shfl_xor(lmax, o, 64));
    int wid = threadIdx.x >> 6;
    if ((threadIdx.x & 63) == 0) red[wid] = lmax;
    __syncthreads();
    float Mx = fmaxf(fmaxf(red[0], red[1]), fmaxf(red[2], red[3]));

    float lsum = 0.f;
    for (int j = threadIdx.x; j < n; j += 256) lsum += __expf((srow[j] - Mx) * 0.03125f);
    for (int o = 32; o > 0; o >>= 1) lsum += __shfl_xor(lsum, o, 64);
    if ((threadIdx.x & 63) == 0) red[4 + wid] = lsum;
    __syncthreads();
    float inv = 1.0f / (red[4] + red[5] + red[6] + red[7]);

    for (int j = threadIdx.x; j < S; j += 256) {
        float v = (j < n) ? __expf((srow[j] - Mx) * 0.03125f) * inv : 0.f;
        prow[j] = f2b(v);
    }
}

// ---------------- V transpose: qkv[.,2048+d] -> vt[b][d][s] -----------------
__global__ __launch_bounds__(256) void transpose_v_kernel(const u16* __restrict__ qkv,
                                                          u16* __restrict__ vt) {
    int b  = blockIdx.z;
    int s0 = blockIdx.x * 64;
    int d0 = blockIdx.y * 64;
    __shared__ __align__(16) u16 tile[64][80];
    int tid = threadIdx.x;
    for (int c = tid; c < 512; c += 256) {
        int r = c >> 3, c8 = (c & 7) * 8;
        *(i32x4*)&tile[r][c8] =
            *(const i32x4*)(qkv + (long long)(b * 2048 + s0 + r) * 3072 + 2048 + d0 + c8);
    }
    __syncthreads();
    for (int c = tid; c < 512; c += 256) {
        int dd = c >> 3, s8 = (c & 7) * 8;
        alignas(16) u16 tmp[8];
#pragma unroll
        for (int e = 0; e < 8; e++) tmp[e] = tile[s8 + e][dd];
        *(i32x4*)(vt + ((long long)b * 1024 + d0 + dd) * 2048 + s0 + s8) = *(i32x4*)tmp;
    }
}

extern "C" void kernel_launch(void* const* d_in, const int* in_sizes, int n_in,
                              void* d_out, int out_size, void* d_ws, size_t ws_size,
                              hipStream_t stream) {
    const float* x  = (const float*)d_in[0];
    const float* wq = (const float*)d_in[1];
    const float* wk = (const float*)d_in[2];
    const float* wv = (const float*)d_in[3];
    float* out = (float*)d_out;

    char* ws = (char*)d_ws;
    // layout (bytes): xb 16M | wb 6M | qkv 48M | scores 64M | P 32M | vt 16M
    u16*   xb  = (u16*)  (ws);
    u16*   wb  = (u16*)  (ws + 16777216LL);
    u16*   qkv = (u16*)  (ws + 23068672LL);
    float* sc  = (float*)(ws + 73400320LL);
    u16*   P   = (u16*)  (ws + 140509184LL);
    u16*   vt  = (u16*)  (ws + 174063616LL);   // total 190,840,832 bytes

    // 1. casts
    cast_kernel<<<8192, 256, 0, stream>>>(x,  xb, 8388608);
    cast_kernel<<<1024, 256, 0, stream>>>(wq, wb,            1048576);
    cast_kernel<<<1024, 256, 0, stream>>>(wk, wb + 1048576,  1048576);
    cast_kernel<<<1024, 256, 0, stream>>>(wv, wb + 2097152,  1048576);

    // 2. QKV projection: [8192,1024] x [3072,1024]^T -> qkv bf16 [8192,3072]
    gemm_bt<0, u16><<<dim3(24, 64, 1), 256, 0, stream>>>(
        xb, 0, 1024, wb, 0, 1024, qkv, 0, 3072, 8192, 3072, 1024);

    // 3. V transpose (per batch): vt[b][d][s]
    transpose_v_kernel<<<dim3(32, 16, 4), 256, 0, stream>>>(qkv, vt);

    // 4. scores_b = Q_b K_b^T, causal tile-skip, fp32 out
    gemm_bt<1, float><<<dim3(16, 16, 4), 256, 0, stream>>>(
        qkv,        2048LL * 3072, 3072,
        qkv + 1024, 2048LL * 3072, 3072,
        sc,         2048LL * 2048, 2048, 2048, 2048, 1024);

    // 5. causal softmax -> P bf16
    softmax_kernel<<<8192, 256, 0, stream>>>(sc, P);

    // 6. out_b = P_b V_b  (as P_b @ vt_b^T, K truncated per row tile), fp32
    gemm_bt<2, float><<<dim3(8, 16, 4), 256, 0, stream>>>(
        P,  2048LL * 2048, 2048,
        vt, 1024LL * 2048, 2048,
        out, 2048LL * 1024, 1024, 2048, 1024, 2048);
}

// Round 2
// 305.416 us; speedup vs baseline: 1.0370x; 1.0370x over previous
//
#include <hip/hip_runtime.h>
#include <hip/hip_bf16.h>

// Causal attention, B=4 S=2048 E=1024 D=1024, fp32 in/out.
// Round 2: gemm_bt staging via __builtin_amdgcn_global_load_lds width=16
// (m93->m97 ladder step). Everything else identical to round 1.

typedef unsigned short u16;
typedef __attribute__((ext_vector_type(4))) u16   u16x4;
typedef __attribute__((ext_vector_type(8))) short short8;
typedef __attribute__((ext_vector_type(4))) float f32x4;
typedef __attribute__((ext_vector_type(4))) int   i32x4;

__device__ inline u16 f2b(float v) {
    __hip_bfloat16 b = __float2bfloat16(v);
    return *reinterpret_cast<u16*>(&b);
}

template <typename T> __device__ inline void store_elem(T* p, float v);
template <> __device__ inline void store_elem<float>(float* p, float v) { *p = v; }
template <> __device__ inline void store_elem<u16>(u16* p, float v)     { *p = f2b(v); }

// async global->LDS 16B per lane; LDS dest must be wave-uniform base + lane*16
__device__ inline void gload_lds16(const u16* g, u16* l) {
    __builtin_amdgcn_global_load_lds(
        (const __attribute__((address_space(1))) void*)g,
        (__attribute__((address_space(3))) void*)l, 16, 0, 0);
}

// ---------------- fp32 -> bf16 cast, 4 elems/thread ----------------
__global__ __launch_bounds__(256) void cast_kernel(const float* __restrict__ src,
                                                   u16* __restrict__ dst, int n) {
    int idx = (blockIdx.x * 256 + threadIdx.x) * 4;
    if (idx >= n) return;
    float4 v = *(const float4*)(src + idx);
    u16x4 o;
    o.x = f2b(v.x); o.y = f2b(v.y); o.z = f2b(v.z); o.w = f2b(v.w);
    *(u16x4*)(dst + idx) = o;
}

// ---------------- BT-GEMM: C[M,N] = A[M,K] * B[N,K]^T (bf16 in, fp32 acc) ---
// MODE 0: plain. MODE 1: causal tile-skip (skip if n0 > m0). MODE 2: K
// truncated to m0+128 (PV with causal-zero P). All dims multiples of tile.
#define MT 128
#define NT 128
#define BK 32

template <int MODE, typename OutT>
__global__ __launch_bounds__(256) void gemm_bt(
    const u16* __restrict__ A, long long strideA, int lda,
    const u16* __restrict__ B, long long strideB, int ldb,
    OutT* __restrict__ C, long long strideC, int ldc,
    int M, int N, int K)
{
    const int m0 = blockIdx.y * MT;
    const int n0 = blockIdx.x * NT;
    if (MODE == 1 && n0 > m0) return;           // tile fully masked
    int Keff = K;
    if (MODE == 2) Keff = min(K, m0 + MT);      // P[m,t]=0 for t>m

    const u16* Ab = A + (long long)blockIdx.z * strideA;
    const u16* Bb = B + (long long)blockIdx.z * strideB;
    OutT*      Cb = C + (long long)blockIdx.z * strideC;

    __shared__ __align__(16) u16 As[MT * BK];
    __shared__ __align__(16) u16 Bs[NT * BK];

    const int tid  = threadIdx.x;
    const int lane = tid & 63;
    const int wave = tid >> 6;
    const int quad = lane >> 4;
    const int r16  = lane & 15;
    const int mw   = (wave >> 1) * 64;
    const int nw   = (wave & 1) * 64;

    // staging addresses: chunk c -> LDS byte offset c*16 (lane-contiguous
    // within each wave => legal global_load_lds dest), global row c>>2,
    // k-offset (c&3)*8 elems.
    const int c0 = tid, c1 = tid + 256;
    const int r0 = c0 >> 2, k0 = (c0 & 3) * 8;
    const int r1 = c1 >> 2, k1 = (c1 & 3) * 8;
    const u16* a0 = Ab + (long long)(m0 + r0) * lda + k0;
    const u16* a1 = Ab + (long long)(m0 + r1) * lda + k1;
    const u16* b0 = Bb + (long long)(n0 + r0) * ldb + k0;
    const u16* b1 = Bb + (long long)(n0 + r1) * ldb + k1;

    f32x4 acc[4][4] = {};

    for (int kk = 0; kk < Keff; kk += BK) {
        __syncthreads();
        gload_lds16(a0 + kk, &As[c0 * 8]);
        gload_lds16(a1 + kk, &As[c1 * 8]);
        gload_lds16(b0 + kk, &Bs[c0 * 8]);
        gload_lds16(b1 + kk, &Bs[c1 * 8]);
        __syncthreads();

        short8 af[4], bf[4];
#pragma unroll
        for (int i = 0; i < 4; i++)
            af[i] = *(const short8*)&As[(mw + i * 16 + r16) * BK + quad * 8];
#pragma unroll
        for (int j = 0; j < 4; j++)
            bf[j] = *(const short8*)&Bs[(nw + j * 16 + r16) * BK + quad * 8];
#pragma unroll
        for (int i = 0; i < 4; i++)
#pragma unroll
            for (int j = 0; j < 4; j++)
                acc[i][j] = __builtin_amdgcn_mfma_f32_16x16x32_bf16(af[i], bf[j], acc[i][j], 0, 0, 0);
    }

    // epilogue: C/D layout col=lane&15, row=quad*4+reg
#pragma unroll
    for (int i = 0; i < 4; i++)
#pragma unroll
        for (int j = 0; j < 4; j++)
#pragma unroll
            for (int r = 0; r < 4; r++) {
                int m = m0 + mw + i * 16 + quad * 4 + r;
                int n = n0 + nw + j * 16 + r16;
                store_elem(&Cb[(long long)m * ldc + n], acc[i][j][r]);
            }
}

// ---------------- causal softmax over fp32 scores -> bf16 P -----------------
// one block per row; softmax(scores/32) over j<=i, zeros elsewhere.
__global__ __launch_bounds__(256) void softmax_kernel(const float* __restrict__ sc,
                                                      u16* __restrict__ P) {
    const int S = 2048;
    int row = blockIdx.x;            // b*S + i
    int i   = row & (S - 1);
    const float* srow = sc + (long long)row * S;
    u16*         prow = P  + (long long)row * S;
    int n = i + 1;

    __shared__ float red[8];
    float lmax = -1e30f;
    for (int j = threadIdx.x; j < n; j += 256) lmax = fmaxf(lmax, srow[j]);
    for (int o = 32; o > 0; o >>= 1) lmax = fmaxf(lmax, __shfl_xor(lmax, o, 64));
    int wid = threadIdx.x >> 6;
    if ((threadIdx.x & 63) == 0) red[wid] = lmax;
    __syncthreads();
    float Mx = fmaxf(fmaxf(red[0], red[1]), fmaxf(red[2], red[3]));

    float lsum = 0.f;
    for (int j = threadIdx.x; j < n; j += 256) lsum += __expf((srow[j] - Mx) * 0.03125f);
    for (int o = 32; o > 0; o >>= 1) lsum += __shfl_xor(lsum, o, 64);
    if ((threadIdx.x & 63) == 0) red[4 + wid] = lsum;
    __syncthreads();
    float inv = 1.0f / (red[4] + red[5] + red[6] + red[7]);

    for (int j = threadIdx.x; j < S; j += 256) {
        float v = (j < n) ? __expf((srow[j] - Mx) * 0.03125f) * inv : 0.f;
        prow[j] = f2b(v);
    }
}

// ---------------- V transpose: qkv[.,2048+d] -> vt[b][d][s] -----------------
__global__ __launch_bounds__(256) void transpose_v_kernel(const u16* __restrict__ qkv,
                                                          u16* __restrict__ vt) {
    int b  = blockIdx.z;
    int s0 = blockIdx.x * 64;
    int d0 = blockIdx.y * 64;
    __shared__ __align__(16) u16 tile[64][80];
    int tid = threadIdx.x;
    for (int c = tid; c < 512; c += 256) {
        int r = c >> 3, c8 = (c & 7) * 8;
        *(i32x4*)&tile[r][c8] =
            *(const i32x4*)(qkv + (long long)(b * 2048 + s0 + r) * 3072 + 2048 + d0 + c8);
    }
    __syncthreads();
    for (int c = tid; c < 512; c += 256) {
        int dd = c >> 3, s8 = (c & 7) * 8;
        alignas(16) u16 tmp[8];
#pragma unroll
        for (int e = 0; e < 8; e++) tmp[e] = tile[s8 + e][dd];
        *(i32x4*)(vt + ((long long)b * 1024 + d0 + dd) * 2048 + s0 + s8) = *(i32x4*)tmp;
    }
}

extern "C" void kernel_launch(void* const* d_in, const int* in_sizes, int n_in,
                              void* d_out, int out_size, void* d_ws, size_t ws_size,
                              hipStream_t stream) {
    const float* x  = (const float*)d_in[0];
    const float* wq = (const float*)d_in[1];
    const float* wk = (const float*)d_in[2];
    const float* wv = (const float*)d_in[3];
    float* out = (float*)d_out;

    char* ws = (char*)d_ws;
    // layout (bytes): xb 16M | wb 6M | qkv 48M | scores 64M | P 32M | vt 16M
    u16*   xb  = (u16*)  (ws);
    u16*   wb  = (u16*)  (ws + 16777216LL);
    u16*   qkv = (u16*)  (ws + 23068672LL);
    float* sc  = (float*)(ws + 73400320LL);
    u16*   P   = (u16*)  (ws + 140509184LL);
    u16*   vt  = (u16*)  (ws + 174063616LL);   // total 190,840,832 bytes

    // 1. casts
    cast_kernel<<<8192, 256, 0, stream>>>(x,  xb, 8388608);
    cast_kernel<<<1024, 256, 0, stream>>>(wq, wb,            1048576);
    cast_kernel<<<1024, 256, 0, stream>>>(wk, wb + 1048576,  1048576);
    cast_kernel<<<1024, 256, 0, stream>>>(wv, wb + 2097152,  1048576);

    // 2. QKV projection: [8192,1024] x [3072,1024]^T -> qkv bf16 [8192,3072]
    gemm_bt<0, u16><<<dim3(24, 64, 1), 256, 0, stream>>>(
        xb, 0, 1024, wb, 0, 1024, qkv, 0, 3072, 8192, 3072, 1024);

    // 3. V transpose (per batch): vt[b][d][s]
    transpose_v_kernel<<<dim3(32, 16, 4), 256, 0, stream>>>(qkv, vt);

    // 4. scores_b = Q_b K_b^T, causal tile-skip, fp32 out
    gemm_bt<1, float><<<dim3(16, 16, 4), 256, 0, stream>>>(
        qkv,        2048LL * 3072, 3072,
        qkv + 1024, 2048LL * 3072, 3072,
        sc,         2048LL * 2048, 2048, 2048, 2048, 1024);

    // 5. causal softmax -> P bf16
    softmax_kernel<<<8192, 256, 0, stream>>>(sc, P);

    // 6. out_b = P_b V_b  (as P_b @ vt_b^T, K truncated per row tile), fp32
    gemm_bt<2, float><<<dim3(8, 16, 4), 256, 0, stream>>>(
        P,  2048LL * 2048, 2048,
        vt, 1024LL * 2048, 2048,
        out, 2048LL * 1024, 1024, 2048, 1024, 2048);
}

// Round 3
// 279.356 us; speedup vs baseline: 1.1338x; 1.0933x over previous
//
#include <hip/hip_runtime.h>
#include <hip/hip_bf16.h>

// Causal attention, B=4 S=2048 E=1024 D=1024, fp32 in/out.
// Round 3: BK=64 via two stride-64B half-buffers (halves barrier count,
// keeps m97's frag layout), scores grid = triangular tiles only,
// PV heavy-rows-first, merged weight casts.

typedef unsigned short u16;
typedef __attribute__((ext_vector_type(4))) u16   u16x4;
typedef __attribute__((ext_vector_type(8))) short short8;
typedef __attribute__((ext_vector_type(4))) float f32x4;
typedef __attribute__((ext_vector_type(4))) int   i32x4;

__device__ inline u16 f2b(float v) {
    __hip_bfloat16 b = __float2bfloat16(v);
    return *reinterpret_cast<u16*>(&b);
}

template <typename T> __device__ inline void store_elem(T* p, float v);
template <> __device__ inline void store_elem<float>(float* p, float v) { *p = v; }
template <> __device__ inline void store_elem<u16>(u16* p, float v)     { *p = f2b(v); }

// async global->LDS 16B per lane; LDS dest must be wave-uniform base + lane*16
__device__ inline void gload_lds16(const u16* g, u16* l) {
    __builtin_amdgcn_global_load_lds(
        (const __attribute__((address_space(1))) void*)g,
        (__attribute__((address_space(3))) void*)l, 16, 0, 0);
}

// ---------------- fp32 -> bf16 casts ----------------
__global__ __launch_bounds__(256) void cast_kernel(const float* __restrict__ src,
                                                   u16* __restrict__ dst, int n) {
    int idx = (blockIdx.x * 256 + threadIdx.x) * 4;
    if (idx >= n) return;
    float4 v = *(const float4*)(src + idx);
    u16x4 o;
    o.x = f2b(v.x); o.y = f2b(v.y); o.z = f2b(v.z); o.w = f2b(v.w);
    *(u16x4*)(dst + idx) = o;
}

// 3 weights in one launch: blockIdx.y selects the source tensor
__global__ __launch_bounds__(256) void cast3_kernel(const float* __restrict__ s0,
                                                    const float* __restrict__ s1,
                                                    const float* __restrict__ s2,
                                                    u16* __restrict__ dst, int n) {
    const float* src = (blockIdx.y == 0) ? s0 : (blockIdx.y == 1) ? s1 : s2;
    int idx = (blockIdx.x * 256 + threadIdx.x) * 4;
    if (idx >= n) return;
    float4 v = *(const float4*)(src + idx);
    u16x4 o;
    o.x = f2b(v.x); o.y = f2b(v.y); o.z = f2b(v.z); o.w = f2b(v.w);
    *(u16x4*)(dst + (long long)blockIdx.y * n + idx) = o;
}

// ---------------- BT-GEMM: C[M,N] = A[M,K] * B[N,K]^T (bf16 in, fp32 acc) ---
// MODE 0: plain. MODE 1: causal, grid.x enumerates lower-tri tiles only.
// MODE 2: K truncated to m0+128 (PV, causal-zero P), heavy rows first.
// BK=64 as two 32-wide half-buffers (row stride stays 64B per half).
#define MT 128
#define NT 128
#define BKH 32
#define HSZ (MT * BKH)   // elems per half buffer = 4096

template <int MODE, typename OutT>
__global__ __launch_bounds__(256) void gemm_bt(
    const u16* __restrict__ A, long long strideA, int lda,
    const u16* __restrict__ B, long long strideB, int ldb,
    OutT* __restrict__ C, long long strideC, int ldc,
    int M, int N, int K)
{
    int m0, n0;
    if (MODE == 1) {
        // triangular decode: blockIdx.x in [0, T*(T+1)/2)
        int t = blockIdx.x;
        float ff = sqrtf(8.0f * t + 1.0f);
        int m = (int)((ff - 1.0f) * 0.5f);
        while ((m + 1) * (m + 2) / 2 <= t) m++;
        while (m * (m + 1) / 2 > t) m--;
        m0 = m * MT;
        n0 = (t - m * (m + 1) / 2) * NT;
    } else if (MODE == 2) {
        m0 = (gridDim.y - 1 - blockIdx.y) * MT;   // heavy (large Keff) first
        n0 = blockIdx.x * NT;
    } else {
        m0 = blockIdx.y * MT;
        n0 = blockIdx.x * NT;
    }
    int Keff = K;
    if (MODE == 2) Keff = min(K, m0 + MT);      // P[m,t]=0 for t>m

    const u16* Ab = A + (long long)blockIdx.z * strideA;
    const u16* Bb = B + (long long)blockIdx.z * strideB;
    OutT*      Cb = C + (long long)blockIdx.z * strideC;

    __shared__ __align__(16) u16 As[2 * HSZ];
    __shared__ __align__(16) u16 Bs[2 * HSZ];

    const int tid  = threadIdx.x;
    const int lane = tid & 63;
    const int wave = tid >> 6;
    const int quad = lane >> 4;
    const int r16  = lane & 15;
    const int mw   = (wave >> 1) * 64;
    const int nw   = (wave & 1) * 64;

    // staging: chunk c -> LDS byte offset c*16 within a half buffer
    // (lane-contiguous => legal global_load_lds dest); row c>>2, k (c&3)*8
    const int c0 = tid, c1 = tid + 256;
    const int r0 = c0 >> 2, k0 = (c0 & 3) * 8;
    const int r1 = c1 >> 2, k1 = (c1 & 3) * 8;
    const u16* a0 = Ab + (long long)(m0 + r0) * lda + k0;
    const u16* a1 = Ab + (long long)(m0 + r1) * lda + k1;
    const u16* b0 = Bb + (long long)(n0 + r0) * ldb + k0;
    const u16* b1 = Bb + (long long)(n0 + r1) * ldb + k1;

    f32x4 acc[4][4] = {};

    for (int kk = 0; kk < Keff; kk += 2 * BKH) {
        __syncthreads();
        gload_lds16(a0 + kk,        &As[c0 * 8]);
        gload_lds16(a1 + kk,        &As[c1 * 8]);
        gload_lds16(a0 + kk + BKH,  &As[HSZ + c0 * 8]);
        gload_lds16(a1 + kk + BKH,  &As[HSZ + c1 * 8]);
        gload_lds16(b0 + kk,        &Bs[c0 * 8]);
        gload_lds16(b1 + kk,        &Bs[c1 * 8]);
        gload_lds16(b0 + kk + BKH,  &Bs[HSZ + c0 * 8]);
        gload_lds16(b1 + kk + BKH,  &Bs[HSZ + c1 * 8]);
        __syncthreads();

#pragma unroll
        for (int h = 0; h < 2; h++) {
            short8 af[4], bf[4];
#pragma unroll
            for (int i = 0; i < 4; i++)
                af[i] = *(const short8*)&As[h * HSZ + (mw + i * 16 + r16) * BKH + quad * 8];
#pragma unroll
            for (int j = 0; j < 4; j++)
                bf[j] = *(const short8*)&Bs[h * HSZ + (nw + j * 16 + r16) * BKH + quad * 8];
#pragma unroll
            for (int i = 0; i < 4; i++)
#pragma unroll
                for (int j = 0; j < 4; j++)
                    acc[i][j] = __builtin_amdgcn_mfma_f32_16x16x32_bf16(af[i], bf[j], acc[i][j], 0, 0, 0);
        }
    }

    // epilogue: C/D layout col=lane&15, row=quad*4+reg
#pragma unroll
    for (int i = 0; i < 4; i++)
#pragma unroll
        for (int j = 0; j < 4; j++)
#pragma unroll
            for (int r = 0; r < 4; r++) {
                int m = m0 + mw + i * 16 + quad * 4 + r;
                int n = n0 + nw + j * 16 + r16;
                store_elem(&Cb[(long long)m * ldc + n], acc[i][j][r]);
            }
}

// ---------------- causal softmax over fp32 scores -> bf16 P -----------------
// one block per row; softmax(scores/32) over j<=i, zeros elsewhere.
__global__ __launch_bounds__(256) void softmax_kernel(const float* __restrict__ sc,
                                                      u16* __restrict__ P) {
    const int S = 2048;
    int row = blockIdx.x;            // b*S + i
    int i   = row & (S - 1);
    const float* srow = sc + (long long)row * S;
    u16*         prow = P  + (long long)row * S;
    int n = i + 1;

    __shared__ float red[8];
    float lmax = -1e30f;
    for (int j = threadIdx.x; j < n; j += 256) lmax = fmaxf(lmax, srow[j]);
    for (int o = 32; o > 0; o >>= 1) lmax = fmaxf(lmax, __shfl_xor(lmax, o, 64));
    int wid = threadIdx.x >> 6;
    if ((threadIdx.x & 63) == 0) red[wid] = lmax;
    __syncthreads();
    float Mx = fmaxf(fmaxf(red[0], red[1]), fmaxf(red[2], red[3]));

    float lsum = 0.f;
    for (int j = threadIdx.x; j < n; j += 256) lsum += __expf((srow[j] - Mx) * 0.03125f);
    for (int o = 32; o > 0; o >>= 1) lsum += __shfl_xor(lsum, o, 64);
    if ((threadIdx.x & 63) == 0) red[4 + wid] = lsum;
    __syncthreads();
    float inv = 1.0f / (red[4] + red[5] + red[6] + red[7]);

    for (int j = threadIdx.x; j < S; j += 256) {
        float v = (j < n) ? __expf((srow[j] - Mx) * 0.03125f) * inv : 0.f;
        prow[j] = f2b(v);
    }
}

// ---------------- V transpose: qkv[.,2048+d] -> vt[b][d][s] -----------------
__global__ __launch_bounds__(256) void transpose_v_kernel(const u16* __restrict__ qkv,
                                                          u16* __restrict__ vt) {
    int b  = blockIdx.z;
    int s0 = blockIdx.x * 64;
    int d0 = blockIdx.y * 64;
    __shared__ __align__(16) u16 tile[64][80];
    int tid = threadIdx.x;
    for (int c = tid; c < 512; c += 256) {
        int r = c >> 3, c8 = (c & 7) * 8;
        *(i32x4*)&tile[r][c8] =
            *(const i32x4*)(qkv + (long long)(b * 2048 + s0 + r) * 3072 + 2048 + d0 + c8);
    }
    __syncthreads();
    for (int c = tid; c < 512; c += 256) {
        int dd = c >> 3, s8 = (c & 7) * 8;
        alignas(16) u16 tmp[8];
#pragma unroll
        for (int e = 0; e < 8; e++) tmp[e] = tile[s8 + e][dd];
        *(i32x4*)(vt + ((long long)b * 1024 + d0 + dd) * 2048 + s0 + s8) = *(i32x4*)tmp;
    }
}

extern "C" void kernel_launch(void* const* d_in, const int* in_sizes, int n_in,
                              void* d_out, int out_size, void* d_ws, size_t ws_size,
                              hipStream_t stream) {
    const float* x  = (const float*)d_in[0];
    const float* wq = (const float*)d_in[1];
    const float* wk = (const float*)d_in[2];
    const float* wv = (const float*)d_in[3];
    float* out = (float*)d_out;

    char* ws = (char*)d_ws;
    // layout (bytes): xb 16M | wb 6M | qkv 48M | scores 64M | P 32M | vt 16M
    u16*   xb  = (u16*)  (ws);
    u16*   wb  = (u16*)  (ws + 16777216LL);
    u16*   qkv = (u16*)  (ws + 23068672LL);
    float* sc  = (float*)(ws + 73400320LL);
    u16*   P   = (u16*)  (ws + 140509184LL);
    u16*   vt  = (u16*)  (ws + 174063616LL);   // total 190,840,832 bytes

    // 1. casts
    cast_kernel<<<8192, 256, 0, stream>>>(x, xb, 8388608);
    cast3_kernel<<<dim3(1024, 3, 1), 256, 0, stream>>>(wq, wk, wv, wb, 1048576);

    // 2. QKV projection: [8192,1024] x [3072,1024]^T -> qkv bf16 [8192,3072]
    gemm_bt<0, u16><<<dim3(24, 64, 1), 256, 0, stream>>>(
        xb, 0, 1024, wb, 0, 1024, qkv, 0, 3072, 8192, 3072, 1024);

    // 3. V transpose (per batch): vt[b][d][s]
    transpose_v_kernel<<<dim3(32, 16, 4), 256, 0, stream>>>(qkv, vt);

    // 4. scores_b = Q_b K_b^T, triangular tiles only (16*17/2 = 136 per batch)
    gemm_bt<1, float><<<dim3(136, 1, 4), 256, 0, stream>>>(
        qkv,        2048LL * 3072, 3072,
        qkv + 1024, 2048LL * 3072, 3072,
        sc,         2048LL * 2048, 2048, 2048, 2048, 1024);

    // 5. causal softmax -> P bf16
    softmax_kernel<<<8192, 256, 0, stream>>>(sc, P);

    // 6. out_b = P_b V_b  (as P_b @ vt_b^T, K truncated per row tile), fp32
    gemm_bt<2, float><<<dim3(8, 16, 4), 256, 0, stream>>>(
        P,  2048LL * 2048, 2048,
        vt, 1024LL * 2048, 2048,
        out, 2048LL * 1024, 1024, 2048, 1024, 2048);
}

// Round 4
// 267.579 us; speedup vs baseline: 1.1837x; 1.0440x over previous
//
#include <hip/hip_runtime.h>
#include <hip/hip_bf16.h>

// Causal attention, B=4 S=2048 E=1024 D=1024, fp32 in/out.
// Round 4: bf16 scores, single-pass register-cached softmax, merged casts,
// distinct per-mode GEMM kernel names for profiling. GEMM core = round 3
// (BK=64 two half-buffers, global_load_lds w16, 128x128, 4 waves).

typedef unsigned short u16;
typedef __attribute__((ext_vector_type(4))) u16   u16x4;
typedef __attribute__((ext_vector_type(8))) u16   u16x8;
typedef __attribute__((ext_vector_type(8))) short short8;
typedef __attribute__((ext_vector_type(4))) float f32x4;
typedef __attribute__((ext_vector_type(4))) int   i32x4;

__device__ inline u16 f2b(float v) {
    __hip_bfloat16 b = __float2bfloat16(v);
    return *reinterpret_cast<u16*>(&b);
}
__device__ inline float b2f(u16 v) {
    unsigned int u = ((unsigned int)v) << 16;
    return *reinterpret_cast<float*>(&u);
}

template <typename T> __device__ inline void store_elem(T* p, float v);
template <> __device__ inline void store_elem<float>(float* p, float v) { *p = v; }
template <> __device__ inline void store_elem<u16>(u16* p, float v)     { *p = f2b(v); }

// async global->LDS 16B per lane; LDS dest must be wave-uniform base + lane*16
__device__ inline void gload_lds16(const u16* g, u16* l) {
    __builtin_amdgcn_global_load_lds(
        (const __attribute__((address_space(1))) void*)g,
        (__attribute__((address_space(3))) void*)l, 16, 0, 0);
}

// ---------------- merged fp32 -> bf16 cast: [x | wq | wk | wv] -------------
// dst regions are contiguous in ws (xb then wb), so dst index = flat quad*4.
__global__ __launch_bounds__(256) void cast_all_kernel(
    const float* __restrict__ x,  const float* __restrict__ wq,
    const float* __restrict__ wk, const float* __restrict__ wv,
    u16* __restrict__ dst) {
    int q = blockIdx.x * 256 + threadIdx.x;     // quad index, 2883584 total
    const float* src;
    int sidx;
    if (q < 2097152) { src = x; sidx = q * 4; }
    else {
        int qq = q - 2097152;
        int w  = qq >> 18;                      // 262144 quads per weight
        sidx   = (qq & 262143) * 4;
        src    = (w == 0) ? wq : (w == 1) ? wk : wv;
    }
    float4 v = *(const float4*)(src + sidx);
    u16x4 o;
    o.x = f2b(v.x); o.y = f2b(v.y); o.z = f2b(v.z); o.w = f2b(v.w);
    *(u16x4*)(dst + q * 4) = o;
}

// ---------------- BT-GEMM core: C[M,N] = A[M,K] * B[N,K]^T ------------------
// MODE 0: plain. MODE 1: causal, grid.x enumerates lower-tri tiles only.
// MODE 2: K truncated to m0+128 (PV, causal-zero P), heavy rows first.
#define MT 128
#define NT 128
#define BKH 32
#define HSZ (MT * BKH)   // elems per half buffer = 4096

template <int MODE, typename OutT>
__device__ __forceinline__ void gemm_bt_body(
    const u16* __restrict__ A, long long strideA, int lda,
    const u16* __restrict__ B, long long strideB, int ldb,
    OutT* __restrict__ C, long long strideC, int ldc,
    int M, int N, int K)
{
    int m0, n0;
    if (MODE == 1) {
        int t = blockIdx.x;
        float ff = sqrtf(8.0f * t + 1.0f);
        int m = (int)((ff - 1.0f) * 0.5f);
        while ((m + 1) * (m + 2) / 2 <= t) m++;
        while (m * (m + 1) / 2 > t) m--;
        m0 = m * MT;
        n0 = (t - m * (m + 1) / 2) * NT;
    } else if (MODE == 2) {
        m0 = (gridDim.y - 1 - blockIdx.y) * MT;   // heavy (large Keff) first
        n0 = blockIdx.x * NT;
    } else {
        m0 = blockIdx.y * MT;
        n0 = blockIdx.x * NT;
    }
    int Keff = K;
    if (MODE == 2) Keff = min(K, m0 + MT);      // P[m,t]=0 for t>m

    const u16* Ab = A + (long long)blockIdx.z * strideA;
    const u16* Bb = B + (long long)blockIdx.z * strideB;
    OutT*      Cb = C + (long long)blockIdx.z * strideC;

    __shared__ __align__(16) u16 As[2 * HSZ];
    __shared__ __align__(16) u16 Bs[2 * HSZ];

    const int tid  = threadIdx.x;
    const int lane = tid & 63;
    const int wave = tid >> 6;
    const int quad = lane >> 4;
    const int r16  = lane & 15;
    const int mw   = (wave >> 1) * 64;
    const int nw   = (wave & 1) * 64;

    const int c0 = tid, c1 = tid + 256;
    const int r0 = c0 >> 2, k0 = (c0 & 3) * 8;
    const int r1 = c1 >> 2, k1 = (c1 & 3) * 8;
    const u16* a0 = Ab + (long long)(m0 + r0) * lda + k0;
    const u16* a1 = Ab + (long long)(m0 + r1) * lda + k1;
    const u16* b0 = Bb + (long long)(n0 + r0) * ldb + k0;
    const u16* b1 = Bb + (long long)(n0 + r1) * ldb + k1;

    f32x4 acc[4][4] = {};

    for (int kk = 0; kk < Keff; kk += 2 * BKH) {
        __syncthreads();
        gload_lds16(a0 + kk,        &As[c0 * 8]);
        gload_lds16(a1 + kk,        &As[c1 * 8]);
        gload_lds16(a0 + kk + BKH,  &As[HSZ + c0 * 8]);
        gload_lds16(a1 + kk + BKH,  &As[HSZ + c1 * 8]);
        gload_lds16(b0 + kk,        &Bs[c0 * 8]);
        gload_lds16(b1 + kk,        &Bs[c1 * 8]);
        gload_lds16(b0 + kk + BKH,  &Bs[HSZ + c0 * 8]);
        gload_lds16(b1 + kk + BKH,  &Bs[HSZ + c1 * 8]);
        __syncthreads();

#pragma unroll
        for (int h = 0; h < 2; h++) {
            short8 af[4], bf[4];
#pragma unroll
            for (int i = 0; i < 4; i++)
                af[i] = *(const short8*)&As[h * HSZ + (mw + i * 16 + r16) * BKH + quad * 8];
#pragma unroll
            for (int j = 0; j < 4; j++)
                bf[j] = *(const short8*)&Bs[h * HSZ + (nw + j * 16 + r16) * BKH + quad * 8];
#pragma unroll
            for (int i = 0; i < 4; i++)
#pragma unroll
                for (int j = 0; j < 4; j++)
                    acc[i][j] = __builtin_amdgcn_mfma_f32_16x16x32_bf16(af[i], bf[j], acc[i][j], 0, 0, 0);
        }
    }

    // epilogue: C/D layout col=lane&15, row=quad*4+reg
#pragma unroll
    for (int i = 0; i < 4; i++)
#pragma unroll
        for (int j = 0; j < 4; j++)
#pragma unroll
            for (int r = 0; r < 4; r++) {
                int m = m0 + mw + i * 16 + quad * 4 + r;
                int n = n0 + nw + j * 16 + r16;
                store_elem(&Cb[(long long)m * ldc + n], acc[i][j][r]);
            }
}

// distinct names so rocprof separates the three GEMMs
__global__ __launch_bounds__(256) void gemm_qkv(
    const u16* A, long long sA, int lda, const u16* B, long long sB, int ldb,
    u16* C, long long sC, int ldc, int M, int N, int K) {
    gemm_bt_body<0, u16>(A, sA, lda, B, sB, ldb, C, sC, ldc, M, N, K);
}
__global__ __launch_bounds__(256) void gemm_scores(
    const u16* A, long long sA, int lda, const u16* B, long long sB, int ldb,
    u16* C, long long sC, int ldc, int M, int N, int K) {
    gemm_bt_body<1, u16>(A, sA, lda, B, sB, ldb, C, sC, ldc, M, N, K);
}
__global__ __launch_bounds__(256) void gemm_pv(
    const u16* A, long long sA, int lda, const u16* B, long long sB, int ldb,
    float* C, long long sC, int ldc, int M, int N, int K) {
    gemm_bt_body<2, float>(A, sA, lda, B, sB, ldb, C, sC, ldc, M, N, K);
}

// ---------------- single-pass causal softmax (bf16 in -> bf16 P) -----------
// one block per row; 256 threads x 8 elems register-cached.
__global__ __launch_bounds__(256) void softmax_kernel(const u16* __restrict__ sc,
                                                      u16* __restrict__ P) {
    const int S = 2048;
    int row = blockIdx.x;            // b*S + i
    int i   = row & (S - 1);
    int n   = i + 1;
    const u16* srow = sc + (long long)row * S;
    u16*       prow = P  + (long long)row * S;

    int j0 = threadIdx.x * 8;
    u16x8 raw = *(const u16x8*)(srow + j0);
    float v[8];
#pragma unroll
    for (int e = 0; e < 8; e++) v[e] = (j0 + e < n) ? b2f(raw[e]) : -1e30f;

    __shared__ float red[8];
    float lmax = v[0];
#pragma unroll
    for (int e = 1; e < 8; e++) lmax = fmaxf(lmax, v[e]);
    for (int o = 32; o > 0; o >>= 1) lmax = fmaxf(lmax, __shfl_xor(lmax, o, 64));
    int wid = threadIdx.x >> 6;
    if ((threadIdx.x & 63) == 0) red[wid] = lmax;
    __syncthreads();
    float Mx = fmaxf(fmaxf(red[0], red[1]), fmaxf(red[2], red[3]));

    // exp((s-Mx)/32) = exp2((s-Mx) * (1/(32 ln2)))
    const float C = 0.045112384f;
    float ev[8];
    float lsum = 0.f;
#pragma unroll
    for (int e = 0; e < 8; e++) {
        ev[e] = (j0 + e < n) ? exp2f((v[e] - Mx) * C) : 0.f;
        lsum += ev[e];
    }
    for (int o = 32; o > 0; o >>= 1) lsum += __shfl_xor(lsum, o, 64);
    if ((threadIdx.x & 63) == 0) red[4 + wid] = lsum;
    __syncthreads();
    float inv = 1.0f / (red[4] + red[5] + red[6] + red[7]);

    u16x8 o8;
#pragma unroll
    for (int e = 0; e < 8; e++) o8[e] = f2b(ev[e] * inv);
    *(u16x8*)(prow + j0) = o8;
}

// ---------------- V transpose: qkv[.,2048+d] -> vt[b][d][s] -----------------
__global__ __launch_bounds__(256) void transpose_v_kernel(const u16* __restrict__ qkv,
                                                          u16* __restrict__ vt) {
    int b  = blockIdx.z;
    int s0 = blockIdx.x * 64;
    int d0 = blockIdx.y * 64;
    __shared__ __align__(16) u16 tile[64][80];
    int tid = threadIdx.x;
    for (int c = tid; c < 512; c += 256) {
        int r = c >> 3, c8 = (c & 7) * 8;
        *(i32x4*)&tile[r][c8] =
            *(const i32x4*)(qkv + (long long)(b * 2048 + s0 + r) * 3072 + 2048 + d0 + c8);
    }
    __syncthreads();
    for (int c = tid; c < 512; c += 256) {
        int dd = c >> 3, s8 = (c & 7) * 8;
        alignas(16) u16 tmp[8];
#pragma unroll
        for (int e = 0; e < 8; e++) tmp[e] = tile[s8 + e][dd];
        *(i32x4*)(vt + ((long long)b * 1024 + d0 + dd) * 2048 + s0 + s8) = *(i32x4*)tmp;
    }
}

extern "C" void kernel_launch(void* const* d_in, const int* in_sizes, int n_in,
                              void* d_out, int out_size, void* d_ws, size_t ws_size,
                              hipStream_t stream) {
    const float* x  = (const float*)d_in[0];
    const float* wq = (const float*)d_in[1];
    const float* wk = (const float*)d_in[2];
    const float* wv = (const float*)d_in[3];
    float* out = (float*)d_out;

    char* ws = (char*)d_ws;
    // layout (bytes): xb 16M | wb 6M | qkv 48M | sc(bf16) 32M | P 32M | vt 16M
    u16* xb  = (u16*)(ws);
    u16* wb  = (u16*)(ws + 16777216LL);
    u16* qkv = (u16*)(ws + 23068672LL);
    u16* sc  = (u16*)(ws + 73400320LL);
    u16* P   = (u16*)(ws + 106954752LL);
    u16* vt  = (u16*)(ws + 140509184LL);   // total 157,286,400 bytes

    // 1. casts (x + 3 weights, one dispatch; dst contiguous = xb..wb)
    cast_all_kernel<<<11264, 256, 0, stream>>>(x, wq, wk, wv, xb);

    // 2. QKV projection: [8192,1024] x [3072,1024]^T -> qkv bf16 [8192,3072]
    gemm_qkv<<<dim3(24, 64, 1), 256, 0, stream>>>(
        xb, 0, 1024, wb, 0, 1024, qkv, 0, 3072, 8192, 3072, 1024);

    // 3. V transpose (per batch): vt[b][d][s]
    transpose_v_kernel<<<dim3(32, 16, 4), 256, 0, stream>>>(qkv, vt);

    // 4. scores_b = Q_b K_b^T -> bf16, triangular tiles only (136/batch)
    gemm_scores<<<dim3(136, 1, 4), 256, 0, stream>>>(
        qkv,        2048LL * 3072, 3072,
        qkv + 1024, 2048LL * 3072, 3072,
        sc,         2048LL * 2048, 2048, 2048, 2048, 1024);

    // 5. single-pass causal softmax -> P bf16
    softmax_kernel<<<8192, 256, 0, stream>>>(sc, P);

    // 6. out_b = P_b V_b  (as P_b @ vt_b^T, K truncated per row tile), fp32
    gemm_pv<<<dim3(8, 16, 4), 256, 0, stream>>>(
        P,  2048LL * 2048, 2048,
        vt, 1024LL * 2048, 2048,
        out, 2048LL * 1024, 1024, 2048, 1024, 2048);
}

// Round 5
// 266.704 us; speedup vs baseline: 1.1875x; 1.0033x over previous
//
#include <hip/hip_runtime.h>
#include <hip/hip_bf16.h>

// Causal attention, B=4 S=2048 E=1024 D=1024, fp32 in/out.
// Round 5: PV split-K (cap per-block K at 1024; heavy tiles m>=8 split into
// two chunks, chunk1 -> fp32 partial + combine kernel), longest-K-first
// schedule. Scores/softmax/QKV unchanged from round 4.

typedef unsigned short u16;
typedef __attribute__((ext_vector_type(4))) u16   u16x4;
typedef __attribute__((ext_vector_type(8))) u16   u16x8;
typedef __attribute__((ext_vector_type(8))) short short8;
typedef __attribute__((ext_vector_type(4))) float f32x4;
typedef __attribute__((ext_vector_type(4))) int   i32x4;

__device__ inline u16 f2b(float v) {
    __hip_bfloat16 b = __float2bfloat16(v);
    return *reinterpret_cast<u16*>(&b);
}
__device__ inline float b2f(u16 v) {
    unsigned int u = ((unsigned int)v) << 16;
    return *reinterpret_cast<float*>(&u);
}

template <typename T> __device__ inline void store_elem(T* p, float v);
template <> __device__ inline void store_elem<float>(float* p, float v) { *p = v; }
template <> __device__ inline void store_elem<u16>(u16* p, float v)     { *p = f2b(v); }

// async global->LDS 16B per lane; LDS dest must be wave-uniform base + lane*16
__device__ inline void gload_lds16(const u16* g, u16* l) {
    __builtin_amdgcn_global_load_lds(
        (const __attribute__((address_space(1))) void*)g,
        (__attribute__((address_space(3))) void*)l, 16, 0, 0);
}

// ---------------- merged fp32 -> bf16 cast: [x | wq | wk | wv] -------------
__global__ __launch_bounds__(256) void cast_all_kernel(
    const float* __restrict__ x,  const float* __restrict__ wq,
    const float* __restrict__ wk, const float* __restrict__ wv,
    u16* __restrict__ dst) {
    int q = blockIdx.x * 256 + threadIdx.x;     // quad index, 2883584 total
    const float* src;
    int sidx;
    if (q < 2097152) { src = x; sidx = q * 4; }
    else {
        int qq = q - 2097152;
        int w  = qq >> 18;                      // 262144 quads per weight
        sidx   = (qq & 262143) * 4;
        src    = (w == 0) ? wq : (w == 1) ? wk : wv;
    }
    float4 v = *(const float4*)(src + sidx);
    u16x4 o;
    o.x = f2b(v.x); o.y = f2b(v.y); o.z = f2b(v.z); o.w = f2b(v.w);
    *(u16x4*)(dst + q * 4) = o;
}

// ---------------- BT-GEMM core (QKV / scores) -------------------------------
// MODE 0: plain. MODE 1: causal, grid.x enumerates lower-tri tiles only.
#define MT 128
#define NT 128
#define BKH 32
#define HSZ (MT * BKH)   // elems per half buffer = 4096

template <int MODE, typename OutT>
__device__ __forceinline__ void gemm_bt_body(
    const u16* __restrict__ A, long long strideA, int lda,
    const u16* __restrict__ B, long long strideB, int ldb,
    OutT* __restrict__ C, long long strideC, int ldc,
    int M, int N, int K)
{
    int m0, n0;
    if (MODE == 1) {
        int t = blockIdx.x;
        float ff = sqrtf(8.0f * t + 1.0f);
        int m = (int)((ff - 1.0f) * 0.5f);
        while ((m + 1) * (m + 2) / 2 <= t) m++;
        while (m * (m + 1) / 2 > t) m--;
        m0 = m * MT;
        n0 = (t - m * (m + 1) / 2) * NT;
    } else {
        m0 = blockIdx.y * MT;
        n0 = blockIdx.x * NT;
    }

    const u16* Ab = A + (long long)blockIdx.z * strideA;
    const u16* Bb = B + (long long)blockIdx.z * strideB;
    OutT*      Cb = C + (long long)blockIdx.z * strideC;

    __shared__ __align__(16) u16 As[2 * HSZ];
    __shared__ __align__(16) u16 Bs[2 * HSZ];

    const int tid  = threadIdx.x;
    const int lane = tid & 63;
    const int wave = tid >> 6;
    const int quad = lane >> 4;
    const int r16  = lane & 15;
    const int mw   = (wave >> 1) * 64;
    const int nw   = (wave & 1) * 64;

    const int c0 = tid, c1 = tid + 256;
    const int r0 = c0 >> 2, k0 = (c0 & 3) * 8;
    const int r1 = c1 >> 2, k1 = (c1 & 3) * 8;
    const u16* a0 = Ab + (long long)(m0 + r0) * lda + k0;
    const u16* a1 = Ab + (long long)(m0 + r1) * lda + k1;
    const u16* b0 = Bb + (long long)(n0 + r0) * ldb + k0;
    const u16* b1 = Bb + (long long)(n0 + r1) * ldb + k1;

    f32x4 acc[4][4] = {};

    for (int kk = 0; kk < K; kk += 2 * BKH) {
        __syncthreads();
        gload_lds16(a0 + kk,        &As[c0 * 8]);
        gload_lds16(a1 + kk,        &As[c1 * 8]);
        gload_lds16(a0 + kk + BKH,  &As[HSZ + c0 * 8]);
        gload_lds16(a1 + kk + BKH,  &As[HSZ + c1 * 8]);
        gload_lds16(b0 + kk,        &Bs[c0 * 8]);
        gload_lds16(b1 + kk,        &Bs[c1 * 8]);
        gload_lds16(b0 + kk + BKH,  &Bs[HSZ + c0 * 8]);
        gload_lds16(b1 + kk + BKH,  &Bs[HSZ + c1 * 8]);
        __syncthreads();

#pragma unroll
        for (int h = 0; h < 2; h++) {
            short8 af[4], bf[4];
#pragma unroll
            for (int i = 0; i < 4; i++)
                af[i] = *(const short8*)&As[h * HSZ + (mw + i * 16 + r16) * BKH + quad * 8];
#pragma unroll
            for (int j = 0; j < 4; j++)
                bf[j] = *(const short8*)&Bs[h * HSZ + (nw + j * 16 + r16) * BKH + quad * 8];
#pragma unroll
            for (int i = 0; i < 4; i++)
#pragma unroll
                for (int j = 0; j < 4; j++)
                    acc[i][j] = __builtin_amdgcn_mfma_f32_16x16x32_bf16(af[i], bf[j], acc[i][j], 0, 0, 0);
        }
    }

    // epilogue: C/D layout col=lane&15, row=quad*4+reg
#pragma unroll
    for (int i = 0; i < 4; i++)
#pragma unroll
        for (int j = 0; j < 4; j++)
#pragma unroll
            for (int r = 0; r < 4; r++) {
                int m = m0 + mw + i * 16 + quad * 4 + r;
                int n = n0 + nw + j * 16 + r16;
                store_elem(&Cb[(long long)m * ldc + n], acc[i][j][r]);
            }
}

__global__ __launch_bounds__(256) void gemm_qkv(
    const u16* A, long long sA, int lda, const u16* B, long long sB, int ldb,
    u16* C, long long sC, int ldc, int M, int N, int K) {
    gemm_bt_body<0, u16>(A, sA, lda, B, sB, ldb, C, sC, ldc, M, N, K);
}
__global__ __launch_bounds__(256) void gemm_scores(
    const u16* A, long long sA, int lda, const u16* B, long long sB, int ldb,
    u16* C, long long sC, int ldc, int M, int N, int K) {
    gemm_bt_body<1, u16>(A, sA, lda, B, sB, ldb, C, sC, ldc, M, N, K);
}

// ---------------- PV GEMM, split-K, longest-first schedule ------------------
// out_b = P_b[2048,2048] @ vt_b[1024,2048]^T.  Per batch 192 units:
// chunk0 m=0..15 (K = min(1024, m0+128)), chunk1 m=8..15 (K = (m-7)*128,
// range [1024, m0+128)).  blockIdx.x ordered by descending chunk-K.
// chunk0 -> out directly; chunk1 -> fp32 partial (combined later).
__global__ __launch_bounds__(256) void gemm_pv(
    const u16* __restrict__ P, const u16* __restrict__ vt,
    float* __restrict__ out, float* __restrict__ part)
{
    const int bid = blockIdx.x;
    int m, chunk, n;
    if (bid < 80) {                       // K = 1024 class
        int q = bid >> 3; n = bid & 7;
        if (q < 9) { m = 7 + q; chunk = 0; } else { m = 15; chunk = 1; }
    } else {                              // K = s*128, s = 7..1
        int r = bid - 80; int s = 7 - (r >> 4); int t = r & 15;
        n = t & 7;
        if (t < 8) { m = s - 1; chunk = 0; } else { m = s + 7; chunk = 1; }
    }
    const int m0 = m * MT, n0 = n * NT;
    const int kbeg = chunk ? 1024 : 0;
    const int kend = chunk ? (m0 + MT) : min(1024, m0 + MT);
    const int b = blockIdx.z;

    const u16* Ab = P  + (long long)b * 2048 * 2048;
    const u16* Bb = vt + (long long)b * 1024 * 2048;

    __shared__ __align__(16) u16 As[2 * HSZ];
    __shared__ __align__(16) u16 Bs[2 * HSZ];

    const int tid  = threadIdx.x;
    const int lane = tid & 63;
    const int wave = tid >> 6;
    const int quad = lane >> 4;
    const int r16  = lane & 15;
    const int mw   = (wave >> 1) * 64;
    const int nw   = (wave & 1) * 64;

    const int c0 = tid, c1 = tid + 256;
    const int r0 = c0 >> 2, k0 = (c0 & 3) * 8;
    const int r1 = c1 >> 2, k1 = (c1 & 3) * 8;
    const u16* a0 = Ab + (long long)(m0 + r0) * 2048 + k0;
    const u16* a1 = Ab + (long long)(m0 + r1) * 2048 + k1;
    const u16* b0 = Bb + (long long)(n0 + r0) * 2048 + k0;
    const u16* b1 = Bb + (long long)(n0 + r1) * 2048 + k1;

    f32x4 acc[4][4] = {};

    for (int kk = kbeg; kk < kend; kk += 2 * BKH) {
        __syncthreads();
        gload_lds16(a0 + kk,        &As[c0 * 8]);
        gload_lds16(a1 + kk,        &As[c1 * 8]);
        gload_lds16(a0 + kk + BKH,  &As[HSZ + c0 * 8]);
        gload_lds16(a1 + kk + BKH,  &As[HSZ + c1 * 8]);
        gload_lds16(b0 + kk,        &Bs[c0 * 8]);
        gload_lds16(b1 + kk,        &Bs[c1 * 8]);
        gload_lds16(b0 + kk + BKH,  &Bs[HSZ + c0 * 8]);
        gload_lds16(b1 + kk + BKH,  &Bs[HSZ + c1 * 8]);
        __syncthreads();

#pragma unroll
        for (int h = 0; h < 2; h++) {
            short8 af[4], bf[4];
#pragma unroll
            for (int i = 0; i < 4; i++)
                af[i] = *(const short8*)&As[h * HSZ + (mw + i * 16 + r16) * BKH + quad * 8];
#pragma unroll
            for (int j = 0; j < 4; j++)
                bf[j] = *(const short8*)&Bs[h * HSZ + (nw + j * 16 + r16) * BKH + quad * 8];
#pragma unroll
            for (int i = 0; i < 4; i++)
#pragma unroll
                for (int j = 0; j < 4; j++)
                    acc[i][j] = __builtin_amdgcn_mfma_f32_16x16x32_bf16(af[i], bf[j], acc[i][j], 0, 0, 0);
        }
    }

#pragma unroll
    for (int i = 0; i < 4; i++)
#pragma unroll
        for (int j = 0; j < 4; j++)
#pragma unroll
            for (int r = 0; r < 4; r++) {
                int mg = m0 + mw + i * 16 + quad * 4 + r;
                int ng = n0 + nw + j * 16 + r16;
                if (chunk == 0)
                    out[(long long)b * 2097152 + (long long)mg * 1024 + ng] = acc[i][j][r];
                else
                    part[(long long)b * 1048576 + (long long)(mg - 1024) * 1024 + ng] = acc[i][j][r];
            }
}

// combine: out[b][1024+r][c] += part[b][r][c]; heavy half is contiguous.
__global__ __launch_bounds__(256) void pv_combine(float* __restrict__ out,
                                                  const float* __restrict__ part) {
    long long idx = ((long long)blockIdx.x * 256 + threadIdx.x) * 8;  // < 4M*8
    long long bb = idx >> 20;             // batch
    long long j  = idx & 1048575;
    float* o = out + bb * 2097152 + 1048576 + j;
    const float* p = part + bb * 1048576 + j;
    float4 o0 = *(float4*)o, o1 = *(float4*)(o + 4);
    float4 p0 = *(const float4*)p, p1 = *(const float4*)(p + 4);
    o0.x += p0.x; o0.y += p0.y; o0.z += p0.z; o0.w += p0.w;
    o1.x += p1.x; o1.y += p1.y; o1.z += p1.z; o1.w += p1.w;
    *(float4*)o = o0; *(float4*)(o + 4) = o1;
}

// ---------------- single-pass causal softmax (bf16 in -> bf16 P) -----------
__global__ __launch_bounds__(256) void softmax_kernel(const u16* __restrict__ sc,
                                                      u16* __restrict__ P) {
    const int S = 2048;
    int row = blockIdx.x;            // b*S + i
    int i   = row & (S - 1);
    int n   = i + 1;
    const u16* srow = sc + (long long)row * S;
    u16*       prow = P  + (long long)row * S;

    int j0 = threadIdx.x * 8;
    u16x8 raw = *(const u16x8*)(srow + j0);
    float v[8];
#pragma unroll
    for (int e = 0; e < 8; e++) v[e] = (j0 + e < n) ? b2f(raw[e]) : -1e30f;

    __shared__ float red[8];
    float lmax = v[0];
#pragma unroll
    for (int e = 1; e < 8; e++) lmax = fmaxf(lmax, v[e]);
    for (int o = 32; o > 0; o >>= 1) lmax = fmaxf(lmax, __shfl_xor(lmax, o, 64));
    int wid = threadIdx.x >> 6;
    if ((threadIdx.x & 63) == 0) red[wid] = lmax;
    __syncthreads();
    float Mx = fmaxf(fmaxf(red[0], red[1]), fmaxf(red[2], red[3]));

    // exp((s-Mx)/32) = exp2((s-Mx) * (1/(32 ln2)))
    const float C = 0.045112384f;
    float ev[8];
    float lsum = 0.f;
#pragma unroll
    for (int e = 0; e < 8; e++) {
        ev[e] = (j0 + e < n) ? exp2f((v[e] - Mx) * C) : 0.f;
        lsum += ev[e];
    }
    for (int o = 32; o > 0; o >>= 1) lsum += __shfl_xor(lsum, o, 64);
    if ((threadIdx.x & 63) == 0) red[4 + wid] = lsum;
    __syncthreads();
    float inv = 1.0f / (red[4] + red[5] + red[6] + red[7]);

    u16x8 o8;
#pragma unroll
    for (int e = 0; e < 8; e++) o8[e] = f2b(ev[e] * inv);
    *(u16x8*)(prow + j0) = o8;
}

// ---------------- V transpose: qkv[.,2048+d] -> vt[b][d][s] -----------------
__global__ __launch_bounds__(256) void transpose_v_kernel(const u16* __restrict__ qkv,
                                                          u16* __restrict__ vt) {
    int b  = blockIdx.z;
    int s0 = blockIdx.x * 64;
    int d0 = blockIdx.y * 64;
    __shared__ __align__(16) u16 tile[64][80];
    int tid = threadIdx.x;
    for (int c = tid; c < 512; c += 256) {
        int r = c >> 3, c8 = (c & 7) * 8;
        *(i32x4*)&tile[r][c8] =
            *(const i32x4*)(qkv + (long long)(b * 2048 + s0 + r) * 3072 + 2048 + d0 + c8);
    }
    __syncthreads();
    for (int c = tid; c < 512; c += 256) {
        int dd = c >> 3, s8 = (c & 7) * 8;
        alignas(16) u16 tmp[8];
#pragma unroll
        for (int e = 0; e < 8; e++) tmp[e] = tile[s8 + e][dd];
        *(i32x4*)(vt + ((long long)b * 1024 + d0 + dd) * 2048 + s0 + s8) = *(i32x4*)tmp;
    }
}

extern "C" void kernel_launch(void* const* d_in, const int* in_sizes, int n_in,
                              void* d_out, int out_size, void* d_ws, size_t ws_size,
                              hipStream_t stream) {
    const float* x  = (const float*)d_in[0];
    const float* wq = (const float*)d_in[1];
    const float* wk = (const float*)d_in[2];
    const float* wv = (const float*)d_in[3];
    float* out = (float*)d_out;

    char* ws = (char*)d_ws;
    // layout: xb 16M | wb 6M | qkv 48M | sc 32M | P 32M | vt 16M | part 16M
    u16*   xb   = (u16*)(ws);
    u16*   wb   = (u16*)(ws + 16777216LL);
    u16*   qkv  = (u16*)(ws + 23068672LL);
    u16*   sc   = (u16*)(ws + 73400320LL);
    u16*   P    = (u16*)(ws + 106954752LL);
    u16*   vt   = (u16*)(ws + 140509184LL);
    float* part = (float*)(ws + 157286400LL);   // total 174,063,616 bytes

    // 1. casts (x + 3 weights, one dispatch)
    cast_all_kernel<<<11264, 256, 0, stream>>>(x, wq, wk, wv, xb);

    // 2. QKV projection: [8192,1024] x [3072,1024]^T -> qkv bf16 [8192,3072]
    gemm_qkv<<<dim3(24, 64, 1), 256, 0, stream>>>(
        xb, 0, 1024, wb, 0, 1024, qkv, 0, 3072, 8192, 3072, 1024);

    // 3. V transpose (per batch): vt[b][d][s]
    transpose_v_kernel<<<dim3(32, 16, 4), 256, 0, stream>>>(qkv, vt);

    // 4. scores_b = Q_b K_b^T -> bf16, triangular tiles only (136/batch)
    gemm_scores<<<dim3(136, 1, 4), 256, 0, stream>>>(
        qkv,        2048LL * 3072, 3072,
        qkv + 1024, 2048LL * 3072, 3072,
        sc,         2048LL * 2048, 2048, 2048, 2048, 1024);

    // 5. single-pass causal softmax -> P bf16
    softmax_kernel<<<8192, 256, 0, stream>>>(sc, P);

    // 6. PV split-K + combine
    gemm_pv<<<dim3(192, 1, 4), 256, 0, stream>>>(P, vt, out, part);
    pv_combine<<<2048, 256, 0, stream>>>(out, part);
}

// Round 6
// 263.270 us; speedup vs baseline: 1.2030x; 1.0130x over previous
//
#include <hip/hip_runtime.h>
#include <hip/hip_bf16.h>

// Causal attention, B=4 S=2048 E=1024 D=1024, fp32 in/out.
// Round 6: occupancy fix. GEMM waves were 80 VGPR + 64 AGPR = 144 regs ->
// rounds into the 256-reg class -> 2 waves/SIMD (meas. 26% occ, 3-round QKV
// makespan). __launch_bounds__(256,4) caps at 128 regs -> 4 waves/SIMD;
// 32-bit lane offsets + uniform bases cut addressing VGPRs.

typedef unsigned short u16;
typedef __attribute__((ext_vector_type(4))) u16   u16x4;
typedef __attribute__((ext_vector_type(8))) u16   u16x8;
typedef __attribute__((ext_vector_type(8))) short short8;
typedef __attribute__((ext_vector_type(4))) float f32x4;
typedef __attribute__((ext_vector_type(4))) int   i32x4;

__device__ inline u16 f2b(float v) {
    __hip_bfloat16 b = __float2bfloat16(v);
    return *reinterpret_cast<u16*>(&b);
}
__device__ inline float b2f(u16 v) {
    unsigned int u = ((unsigned int)v) << 16;
    return *reinterpret_cast<float*>(&u);
}

template <typename T> __device__ inline void store_elem(T* p, float v);
template <> __device__ inline void store_elem<float>(float* p, float v) { *p = v; }
template <> __device__ inline void store_elem<u16>(u16* p, float v)     { *p = f2b(v); }

// async global->LDS 16B per lane; LDS dest must be wave-uniform base + lane*16
__device__ inline void gload_lds16(const u16* g, u16* l) {
    __builtin_amdgcn_global_load_lds(
        (const __attribute__((address_space(1))) void*)g,
        (__attribute__((address_space(3))) void*)l, 16, 0, 0);
}

// ---------------- merged fp32 -> bf16 cast: [x | wq | wk | wv] -------------
__global__ __launch_bounds__(256) void cast_all_kernel(
    const float* __restrict__ x,  const float* __restrict__ wq,
    const float* __restrict__ wk, const float* __restrict__ wv,
    u16* __restrict__ dst) {
    int q = blockIdx.x * 256 + threadIdx.x;     // quad index, 2883584 total
    const float* src;
    int sidx;
    if (q < 2097152) { src = x; sidx = q * 4; }
    else {
        int qq = q - 2097152;
        int w  = qq >> 18;                      // 262144 quads per weight
        sidx   = (qq & 262143) * 4;
        src    = (w == 0) ? wq : (w == 1) ? wk : wv;
    }
    float4 v = *(const float4*)(src + sidx);
    u16x4 o;
    o.x = f2b(v.x); o.y = f2b(v.y); o.z = f2b(v.z); o.w = f2b(v.w);
    *(u16x4*)(dst + q * 4) = o;
}

// ---------------- BT-GEMM core -----------------------------------------------
#define MT 128
#define NT 128
#define BKH 32
#define HSZ (MT * BKH)   // elems per half buffer = 4096

// K-loop + epilogue shared by all GEMMs. Addresses: uniform base pointers +
// 32-bit lane offsets (saddr form) to minimize VGPR footprint.
template <typename OutT>
__device__ __forceinline__ void gemm_core(
    const u16* __restrict__ Ab, int lda,
    const u16* __restrict__ Bb, int ldb,
    OutT* __restrict__ Cb, int ldc,
    int m0, int n0, int kbeg, int kend)
{
    __shared__ __align__(16) u16 As[2 * HSZ];
    __shared__ __align__(16) u16 Bs[2 * HSZ];

    const int tid  = threadIdx.x;
    const int lane = tid & 63;
    const int wave = tid >> 6;
    const int quad = lane >> 4;
    const int r16  = lane & 15;
    const int mw   = (wave >> 1) * 64;
    const int nw   = (wave & 1) * 64;

    const int c0 = tid, c1 = tid + 256;
    const int r0 = c0 >> 2, k0 = (c0 & 3) * 8;
    const int r1 = c1 >> 2, k1 = (c1 & 3) * 8;
    // 32-bit element offsets (max ~25M elems, fits)
    const int oa0 = (m0 + r0) * lda + k0;
    const int oa1 = (m0 + r1) * lda + k1;
    const int ob0 = (n0 + r0) * ldb + k0;
    const int ob1 = (n0 + r1) * ldb + k1;

    f32x4 acc[4][4] = {};

    for (int kk = kbeg; kk < kend; kk += 2 * BKH) {
        __syncthreads();
        gload_lds16(Ab + (kk + oa0),        &As[c0 * 8]);
        gload_lds16(Ab + (kk + oa1),        &As[c1 * 8]);
        gload_lds16(Ab + (kk + BKH + oa0),  &As[HSZ + c0 * 8]);
        gload_lds16(Ab + (kk + BKH + oa1),  &As[HSZ + c1 * 8]);
        gload_lds16(Bb + (kk + ob0),        &Bs[c0 * 8]);
        gload_lds16(Bb + (kk + ob1),        &Bs[c1 * 8]);
        gload_lds16(Bb + (kk + BKH + ob0),  &Bs[HSZ + c0 * 8]);
        gload_lds16(Bb + (kk + BKH + ob1),  &Bs[HSZ + c1 * 8]);
        __syncthreads();

#pragma unroll
        for (int h = 0; h < 2; h++) {
            short8 af[4], bf[4];
#pragma unroll
            for (int i = 0; i < 4; i++)
                af[i] = *(const short8*)&As[h * HSZ + (mw + i * 16 + r16) * BKH + quad * 8];
#pragma unroll
            for (int j = 0; j < 4; j++)
                bf[j] = *(const short8*)&Bs[h * HSZ + (nw + j * 16 + r16) * BKH + quad * 8];
#pragma unroll
            for (int i = 0; i < 4; i++)
#pragma unroll
                for (int j = 0; j < 4; j++)
                    acc[i][j] = __builtin_amdgcn_mfma_f32_16x16x32_bf16(af[i], bf[j], acc[i][j], 0, 0, 0);
        }
    }

    // epilogue: C/D layout col=lane&15, row=quad*4+reg
#pragma unroll
    for (int i = 0; i < 4; i++)
#pragma unroll
        for (int j = 0; j < 4; j++)
#pragma unroll
            for (int r = 0; r < 4; r++) {
                int m = m0 + mw + i * 16 + quad * 4 + r;
                int n = n0 + nw + j * 16 + r16;
                store_elem(&Cb[(long long)m * ldc + n], acc[i][j][r]);
            }
}

__global__ __launch_bounds__(256, 4) void gemm_qkv(
    const u16* __restrict__ A, const u16* __restrict__ B, u16* __restrict__ C) {
    // [8192,1024] x [3072,1024]^T -> [8192,3072]
    gemm_core<u16>(A, 1024, B, 1024, C, 3072,
                   blockIdx.y * MT, blockIdx.x * NT, 0, 1024);
}

__global__ __launch_bounds__(256, 4) void gemm_scores(
    const u16* __restrict__ qkv, u16* __restrict__ sc) {
    // per batch: Q[2048,1024(ld3072)] x K^T -> sc[2048,2048], lower-tri tiles
    int t = blockIdx.x;
    float ff = sqrtf(8.0f * t + 1.0f);
    int m = (int)((ff - 1.0f) * 0.5f);
    while ((m + 1) * (m + 2) / 2 <= t) m++;
    while (m * (m + 1) / 2 > t) m--;
    int m0 = m * MT;
    int n0 = (t - m * (m + 1) / 2) * NT;
    const u16* Ab = qkv + (long long)blockIdx.z * 2048 * 3072;
    const u16* Bb = Ab + 1024;
    u16* Cb = sc + (long long)blockIdx.z * 2048 * 2048;
    gemm_core<u16>(Ab, 3072, Bb, 3072, Cb, 2048, m0, n0, 0, 1024);
}

// PV split-K, longest-first schedule: per batch 192 units (see round 5).
__global__ __launch_bounds__(256, 4) void gemm_pv(
    const u16* __restrict__ P, const u16* __restrict__ vt,
    float* __restrict__ out, float* __restrict__ part)
{
    const int bid = blockIdx.x;
    int m, chunk, n;
    if (bid < 80) {                       // K = 1024 class
        int q = bid >> 3; n = bid & 7;
        if (q < 9) { m = 7 + q; chunk = 0; } else { m = 15; chunk = 1; }
    } else {                              // K = s*128, s = 7..1
        int r = bid - 80; int s = 7 - (r >> 4); int t = r & 15;
        n = t & 7;
        if (t < 8) { m = s - 1; chunk = 0; } else { m = s + 7; chunk = 1; }
    }
    const int m0 = m * MT, n0 = n * NT;
    const int kbeg = chunk ? 1024 : 0;
    const int kend = chunk ? (m0 + MT) : min(1024, m0 + MT);
    const int b = blockIdx.z;

    const u16* Ab = P  + (long long)b * 2048 * 2048;
    const u16* Bb = vt + (long long)b * 1024 * 2048;
    if (chunk == 0) {
        float* Cb = out + (long long)b * 2097152;
        gemm_core<float>(Ab, 2048, Bb, 2048, Cb, 1024, m0, n0, kbeg, kend);
    } else {
        float* Cb = part + (long long)b * 1048576 - 1024LL * 1024;  // m-1024 rows
        gemm_core<float>(Ab, 2048, Bb, 2048, Cb, 1024, m0, n0, kbeg, kend);
    }
}

// combine: out[b][1024+r][c] += part[b][r][c]
__global__ __launch_bounds__(256) void pv_combine(float* __restrict__ out,
                                                  const float* __restrict__ part) {
    long long idx = ((long long)blockIdx.x * 256 + threadIdx.x) * 8;
    long long bb = idx >> 20;
    long long j  = idx & 1048575;
    float* o = out + bb * 2097152 + 1048576 + j;
    const float* p = part + bb * 1048576 + j;
    float4 o0 = *(float4*)o, o1 = *(float4*)(o + 4);
    float4 p0 = *(const float4*)p, p1 = *(const float4*)(p + 4);
    o0.x += p0.x; o0.y += p0.y; o0.z += p0.z; o0.w += p0.w;
    o1.x += p1.x; o1.y += p1.y; o1.z += p1.z; o1.w += p1.w;
    *(float4*)o = o0; *(float4*)(o + 4) = o1;
}

// ---------------- single-pass causal softmax (bf16 in -> bf16 P) -----------
__global__ __launch_bounds__(256) void softmax_kernel(const u16* __restrict__ sc,
                                                      u16* __restrict__ P) {
    const int S = 2048;
    int row = blockIdx.x;            // b*S + i
    int i   = row & (S - 1);
    int n   = i + 1;
    const u16* srow = sc + (long long)row * S;
    u16*       prow = P  + (long long)row * S;

    int j0 = threadIdx.x * 8;
    u16x8 raw = *(const u16x8*)(srow + j0);
    float v[8];
#pragma unroll
    for (int e = 0; e < 8; e++) v[e] = (j0 + e < n) ? b2f(raw[e]) : -1e30f;

    __shared__ float red[8];
    float lmax = v[0];
#pragma unroll
    for (int e = 1; e < 8; e++) lmax = fmaxf(lmax, v[e]);
    for (int o = 32; o > 0; o >>= 1) lmax = fmaxf(lmax, __shfl_xor(lmax, o, 64));
    int wid = threadIdx.x >> 6;
    if ((threadIdx.x & 63) == 0) red[wid] = lmax;
    __syncthreads();
    float Mx = fmaxf(fmaxf(red[0], red[1]), fmaxf(red[2], red[3]));

    // exp((s-Mx)/32) = exp2((s-Mx) * (1/(32 ln2)))
    const float C = 0.045112384f;
    float ev[8];
    float lsum = 0.f;
#pragma unroll
    for (int e = 0; e < 8; e++) {
        ev[e] = (j0 + e < n) ? exp2f((v[e] - Mx) * C) : 0.f;
        lsum += ev[e];
    }
    for (int o = 32; o > 0; o >>= 1) lsum += __shfl_xor(lsum, o, 64);
    if ((threadIdx.x & 63) == 0) red[4 + wid] = lsum;
    __syncthreads();
    float inv = 1.0f / (red[4] + red[5] + red[6] + red[7]);

    u16x8 o8;
#pragma unroll
    for (int e = 0; e < 8; e++) o8[e] = f2b(ev[e] * inv);
    *(u16x8*)(prow + j0) = o8;
}

// ---------------- V transpose: qkv[.,2048+d] -> vt[b][d][s] -----------------
__global__ __launch_bounds__(256) void transpose_v_kernel(const u16* __restrict__ qkv,
                                                          u16* __restrict__ vt) {
    int b  = blockIdx.z;
    int s0 = blockIdx.x * 64;
    int d0 = blockIdx.y * 64;
    __shared__ __align__(16) u16 tile[64][80];
    int tid = threadIdx.x;
    for (int c = tid; c < 512; c += 256) {
        int r = c >> 3, c8 = (c & 7) * 8;
        *(i32x4*)&tile[r][c8] =
            *(const i32x4*)(qkv + (long long)(b * 2048 + s0 + r) * 3072 + 2048 + d0 + c8);
    }
    __syncthreads();
    for (int c = tid; c < 512; c += 256) {
        int dd = c >> 3, s8 = (c & 7) * 8;
        alignas(16) u16 tmp[8];
#pragma unroll
        for (int e = 0; e < 8; e++) tmp[e] = tile[s8 + e][dd];
        *(i32x4*)(vt + ((long long)b * 1024 + d0 + dd) * 2048 + s0 + s8) = *(i32x4*)tmp;
    }
}

extern "C" void kernel_launch(void* const* d_in, const int* in_sizes, int n_in,
                              void* d_out, int out_size, void* d_ws, size_t ws_size,
                              hipStream_t stream) {
    const float* x  = (const float*)d_in[0];
    const float* wq = (const float*)d_in[1];
    const float* wk = (const float*)d_in[2];
    const float* wv = (const float*)d_in[3];
    float* out = (float*)d_out;

    char* ws = (char*)d_ws;
    // layout: xb 16M | wb 6M | qkv 48M | sc 32M | P 32M | vt 16M | part 16M
    u16*   xb   = (u16*)(ws);
    u16*   wb   = (u16*)(ws + 16777216LL);
    u16*   qkv  = (u16*)(ws + 23068672LL);
    u16*   sc   = (u16*)(ws + 73400320LL);
    u16*   P    = (u16*)(ws + 106954752LL);
    u16*   vt   = (u16*)(ws + 140509184LL);
    float* part = (float*)(ws + 157286400LL);   // total 174,063,616 bytes

    // 1. casts (x + 3 weights, one dispatch)
    cast_all_kernel<<<11264, 256, 0, stream>>>(x, wq, wk, wv, xb);

    // 2. QKV projection
    gemm_qkv<<<dim3(24, 64, 1), 256, 0, stream>>>(xb, wb, qkv);

    // 3. V transpose (per batch): vt[b][d][s]
    transpose_v_kernel<<<dim3(32, 16, 4), 256, 0, stream>>>(qkv, vt);

    // 4. scores_b = Q_b K_b^T -> bf16, triangular tiles only (136/batch)
    gemm_scores<<<dim3(136, 1, 4), 256, 0, stream>>>(qkv, sc);

    // 5. single-pass causal softmax -> P bf16
    softmax_kernel<<<8192, 256, 0, stream>>>(sc, P);

    // 6. PV split-K + combine
    gemm_pv<<<dim3(192, 1, 4), 256, 0, stream>>>(P, vt, out, part);
    pv_combine<<<2048, 256, 0, stream>>>(out, part);
}

// Round 7
// 255.871 us; speedup vs baseline: 1.2378x; 1.0289x over previous
//
#include <hip/hip_runtime.h>
#include <hip/hip_bf16.h>

// Causal attention, B=4 S=2048 E=1024 D=1024, fp32 in/out.
// Round 7: fuse V-transpose into QKV epilogue (V blocks store transposed
// straight to vt; Q,K pack into dense [8192,2048]); softmax trimmed to the
// causal triangle (loads j<=i, writes to 128-aligned row tile boundary).
// GEMM core unchanged from round 6 (BK=64, global_load_lds w16, 124 regs).

typedef unsigned short u16;
typedef __attribute__((ext_vector_type(4))) u16   u16x4;
typedef __attribute__((ext_vector_type(8))) u16   u16x8;
typedef __attribute__((ext_vector_type(8))) short short8;
typedef __attribute__((ext_vector_type(4))) float f32x4;
typedef __attribute__((ext_vector_type(4))) int   i32x4;

__device__ inline u16 f2b(float v) {
    __hip_bfloat16 b = __float2bfloat16(v);
    return *reinterpret_cast<u16*>(&b);
}
__device__ inline float b2f(u16 v) {
    unsigned int u = ((unsigned int)v) << 16;
    return *reinterpret_cast<float*>(&u);
}

template <typename T> __device__ inline void store_elem(T* p, float v);
template <> __device__ inline void store_elem<float>(float* p, float v) { *p = v; }
template <> __device__ inline void store_elem<u16>(u16* p, float v)     { *p = f2b(v); }

// async global->LDS 16B per lane; LDS dest must be wave-uniform base + lane*16
__device__ inline void gload_lds16(const u16* g, u16* l) {
    __builtin_amdgcn_global_load_lds(
        (const __attribute__((address_space(1))) void*)g,
        (__attribute__((address_space(3))) void*)l, 16, 0, 0);
}

// ---------------- merged fp32 -> bf16 cast: [x | wq | wk | wv] -------------
__global__ __launch_bounds__(256) void cast_all_kernel(
    const float* __restrict__ x,  const float* __restrict__ wq,
    const float* __restrict__ wk, const float* __restrict__ wv,
    u16* __restrict__ dst) {
    int q = blockIdx.x * 256 + threadIdx.x;     // quad index, 2883584 total
    const float* src;
    int sidx;
    if (q < 2097152) { src = x; sidx = q * 4; }
    else {
        int qq = q - 2097152;
        int w  = qq >> 18;                      // 262144 quads per weight
        sidx   = (qq & 262143) * 4;
        src    = (w == 0) ? wq : (w == 1) ? wk : wv;
    }
    float4 v = *(const float4*)(src + sidx);
    u16x4 o;
    o.x = f2b(v.x); o.y = f2b(v.y); o.z = f2b(v.z); o.w = f2b(v.w);
    *(u16x4*)(dst + q * 4) = o;
}

// ---------------- BT-GEMM core -----------------------------------------------
#define MT 128
#define NT 128
#define BKH 32
#define HSZ (MT * BKH)   // elems per half buffer = 4096

// TRANS=0: C[m][n] = val (OutT). TRANS=1: transposed bf16 store into
// vt[b][d][s] (Cb = vt base, n0 = d base, b/s derived from m; M rows are
// b*2048+s with 128-tiles never straddling a batch).
template <int TRANS, typename OutT>
__device__ __forceinline__ void gemm_core(
    const u16* __restrict__ Ab, int lda,
    const u16* __restrict__ Bb, int ldb,
    OutT* __restrict__ Cb, int ldc,
    int m0, int n0, int kbeg, int kend)
{
    __shared__ __align__(16) u16 As[2 * HSZ];
    __shared__ __align__(16) u16 Bs[2 * HSZ];

    const int tid  = threadIdx.x;
    const int lane = tid & 63;
    const int wave = tid >> 6;
    const int quad = lane >> 4;
    const int r16  = lane & 15;
    const int mw   = (wave >> 1) * 64;
    const int nw   = (wave & 1) * 64;

    const int c0 = tid, c1 = tid + 256;
    const int r0 = c0 >> 2, k0 = (c0 & 3) * 8;
    const int r1 = c1 >> 2, k1 = (c1 & 3) * 8;
    const int oa0 = (m0 + r0) * lda + k0;
    const int oa1 = (m0 + r1) * lda + k1;
    const int ob0 = (n0 + r0) * ldb + k0;
    const int ob1 = (n0 + r1) * ldb + k1;

    f32x4 acc[4][4] = {};

    for (int kk = kbeg; kk < kend; kk += 2 * BKH) {
        __syncthreads();
        gload_lds16(Ab + (kk + oa0),        &As[c0 * 8]);
        gload_lds16(Ab + (kk + oa1),        &As[c1 * 8]);
        gload_lds16(Ab + (kk + BKH + oa0),  &As[HSZ + c0 * 8]);
        gload_lds16(Ab + (kk + BKH + oa1),  &As[HSZ + c1 * 8]);
        gload_lds16(Bb + (kk + ob0),        &Bs[c0 * 8]);
        gload_lds16(Bb + (kk + ob1),        &Bs[c1 * 8]);
        gload_lds16(Bb + (kk + BKH + ob0),  &Bs[HSZ + c0 * 8]);
        gload_lds16(Bb + (kk + BKH + ob1),  &Bs[HSZ + c1 * 8]);
        __syncthreads();

#pragma unroll
        for (int h = 0; h < 2; h++) {
            short8 af[4], bf[4];
#pragma unroll
            for (int i = 0; i < 4; i++)
                af[i] = *(const short8*)&As[h * HSZ + (mw + i * 16 + r16) * BKH + quad * 8];
#pragma unroll
            for (int j = 0; j < 4; j++)
                bf[j] = *(const short8*)&Bs[h * HSZ + (nw + j * 16 + r16) * BKH + quad * 8];
#pragma unroll
            for (int i = 0; i < 4; i++)
#pragma unroll
                for (int j = 0; j < 4; j++)
                    acc[i][j] = __builtin_amdgcn_mfma_f32_16x16x32_bf16(af[i], bf[j], acc[i][j], 0, 0, 0);
        }
    }

    // epilogue: C/D layout col=lane&15, row=quad*4+reg
    if (TRANS == 0) {
#pragma unroll
        for (int i = 0; i < 4; i++)
#pragma unroll
            for (int j = 0; j < 4; j++)
#pragma unroll
                for (int r = 0; r < 4; r++) {
                    int m = m0 + mw + i * 16 + quad * 4 + r;
                    int n = n0 + nw + j * 16 + r16;
                    store_elem(&Cb[(long long)m * ldc + n], acc[i][j][r]);
                }
    } else {
#pragma unroll
        for (int i = 0; i < 4; i++)
#pragma unroll
            for (int j = 0; j < 4; j++) {
                int mbase = m0 + mw + i * 16 + quad * 4;      // 4-aligned
                int d     = n0 + nw + j * 16 + r16;
                int b     = mbase >> 11;
                int s     = mbase & 2047;
                u16x4 o;
#pragma unroll
                for (int r = 0; r < 4; r++) o[r] = f2b(acc[i][j][r]);
                *(u16x4*)((u16*)Cb + (((b << 10) + d) * 2048 + s)) = o;
            }
    }
}

// QKV: [8192,1024] x [3072,1024]^T. Blocks x<16 -> qk[8192,2048] (Q|K dense);
// x>=16 -> V, stored transposed into vt[b][d][s].
__global__ __launch_bounds__(256, 4) void gemm_qkv(
    const u16* __restrict__ xb, const u16* __restrict__ wb,
    u16* __restrict__ qk, u16* __restrict__ vt) {
    int bx = blockIdx.x, m0 = blockIdx.y * MT;
    if (bx < 16)
        gemm_core<0, u16>(xb, 1024, wb, 1024, qk, 2048, m0, bx * 128, 0, 1024);
    else
        gemm_core<1, u16>(xb, 1024, wb + 2048 * 1024, 1024, vt, 2048,
                          m0, (bx - 16) * 128, 0, 1024);
}

__global__ __launch_bounds__(256, 4) void gemm_scores(
    const u16* __restrict__ qk, u16* __restrict__ sc) {
    // per batch: Q[2048,1024(ld2048)] x K^T -> sc[2048,2048], lower-tri tiles
    int t = blockIdx.x;
    float ff = sqrtf(8.0f * t + 1.0f);
    int m = (int)((ff - 1.0f) * 0.5f);
    while ((m + 1) * (m + 2) / 2 <= t) m++;
    while (m * (m + 1) / 2 > t) m--;
    int m0 = m * MT;
    int n0 = (t - m * (m + 1) / 2) * NT;
    const u16* Ab = qk + (long long)blockIdx.z * 2048 * 2048;
    const u16* Bb = Ab + 1024;
    u16* Cb = sc + (long long)blockIdx.z * 2048 * 2048;
    gemm_core<0, u16>(Ab, 2048, Bb, 2048, Cb, 2048, m0, n0, 0, 1024);
}

// PV split-K, longest-first schedule: per batch 192 units (see round 5).
__global__ __launch_bounds__(256, 4) void gemm_pv(
    const u16* __restrict__ P, const u16* __restrict__ vt,
    float* __restrict__ out, float* __restrict__ part)
{
    const int bid = blockIdx.x;
    int m, chunk, n;
    if (bid < 80) {                       // K = 1024 class
        int q = bid >> 3; n = bid & 7;
        if (q < 9) { m = 7 + q; chunk = 0; } else { m = 15; chunk = 1; }
    } else {                              // K = s*128, s = 7..1
        int r = bid - 80; int s = 7 - (r >> 4); int t = r & 15;
        n = t & 7;
        if (t < 8) { m = s - 1; chunk = 0; } else { m = s + 7; chunk = 1; }
    }
    const int m0 = m * MT, n0 = n * NT;
    const int kbeg = chunk ? 1024 : 0;
    const int kend = chunk ? (m0 + MT) : min(1024, m0 + MT);
    const int b = blockIdx.z;

    const u16* Ab = P  + (long long)b * 2048 * 2048;
    const u16* Bb = vt + (long long)b * 1024 * 2048;
    if (chunk == 0) {
        float* Cb = out + (long long)b * 2097152;
        gemm_core<0, float>(Ab, 2048, Bb, 2048, Cb, 1024, m0, n0, kbeg, kend);
    } else {
        float* Cb = part + (long long)b * 1048576 - 1024LL * 1024;  // m-1024 rows
        gemm_core<0, float>(Ab, 2048, Bb, 2048, Cb, 1024, m0, n0, kbeg, kend);
    }
}

// combine: out[b][1024+r][c] += part[b][r][c]
__global__ __launch_bounds__(256) void pv_combine(float* __restrict__ out,
                                                  const float* __restrict__ part) {
    long long idx = ((long long)blockIdx.x * 256 + threadIdx.x) * 8;
    long long bb = idx >> 20;
    long long j  = idx & 1048575;
    float* o = out + bb * 2097152 + 1048576 + j;
    const float* p = part + bb * 1048576 + j;
    float4 o0 = *(float4*)o, o1 = *(float4*)(o + 4);
    float4 p0 = *(const float4*)p, p1 = *(const float4*)(p + 4);
    o0.x += p0.x; o0.y += p0.y; o0.z += p0.z; o0.w += p0.w;
    o1.x += p1.x; o1.y += p1.y; o1.z += p1.z; o1.w += p1.w;
    *(float4*)o = o0; *(float4*)(o + 4) = o1;
}

// ---------------- single-pass causal softmax (bf16 in -> bf16 P) -----------
// triangle-trimmed: loads only j<=i, writes only up to the row's 128-aligned
// tile boundary (PV never reads past kend_row = (i & ~127) + 128).
__global__ __launch_bounds__(256) void softmax_kernel(const u16* __restrict__ sc,
                                                      u16* __restrict__ P) {
    const int S = 2048;
    int row = blockIdx.x;            // b*S + i
    int i   = row & (S - 1);
    int n   = i + 1;
    int kendr = (i & ~127) + 128;
    const u16* srow = sc + (long long)row * S;
    u16*       prow = P  + (long long)row * S;

    int j0 = threadIdx.x * 8;
    u16x8 raw = {};
    if (j0 <= i) raw = *(const u16x8*)(srow + j0);
    float v[8];
#pragma unroll
    for (int e = 0; e < 8; e++) v[e] = (j0 + e < n) ? b2f(raw[e]) : -1e30f;

    __shared__ float red[8];
    float lmax = v[0];
#pragma unroll
    for (int e = 1; e < 8; e++) lmax = fmaxf(lmax, v[e]);
    for (int o = 32; o > 0; o >>= 1) lmax = fmaxf(lmax, __shfl_xor(lmax, o, 64));
    int wid = threadIdx.x >> 6;
    if ((threadIdx.x & 63) == 0) red[wid] = lmax;
    __syncthreads();
    float Mx = fmaxf(fmaxf(red[0], red[1]), fmaxf(red[2], red[3]));

    // exp((s-Mx)/32) = exp2((s-Mx) * (1/(32 ln2)))
    const float C = 0.045112384f;
    float ev[8];
    float lsum = 0.f;
#pragma unroll
    for (int e = 0; e < 8; e++) {
        ev[e] = (j0 + e < n) ? exp2f((v[e] - Mx) * C) : 0.f;
        lsum += ev[e];
    }
    for (int o = 32; o > 0; o >>= 1) lsum += __shfl_xor(lsum, o, 64);
    if ((threadIdx.x & 63) == 0) red[4 + wid] = lsum;
    __syncthreads();
    float inv = 1.0f / (red[4] + red[5] + red[6] + red[7]);

    if (j0 < kendr) {
        u16x8 o8;
#pragma unroll
        for (int e = 0; e < 8; e++) o8[e] = f2b(ev[e] * inv);
        *(u16x8*)(prow + j0) = o8;
    }
}

extern "C" void kernel_launch(void* const* d_in, const int* in_sizes, int n_in,
                              void* d_out, int out_size, void* d_ws, size_t ws_size,
                              hipStream_t stream) {
    const float* x  = (const float*)d_in[0];
    const float* wq = (const float*)d_in[1];
    const float* wk = (const float*)d_in[2];
    const float* wv = (const float*)d_in[3];
    float* out = (float*)d_out;

    char* ws = (char*)d_ws;
    // layout: xb 16M | wb 6M | qk 32M | sc 32M | P 32M | vt 16M | part 16M
    u16*   xb   = (u16*)(ws);
    u16*   wb   = (u16*)(ws + 16777216LL);
    u16*   qk   = (u16*)(ws + 23068672LL);
    u16*   sc   = (u16*)(ws + 56623104LL);
    u16*   P    = (u16*)(ws + 90177536LL);
    u16*   vt   = (u16*)(ws + 123731968LL);
    float* part = (float*)(ws + 140509184LL);   // total 157,286,400 bytes

    // 1. casts (x + 3 weights, one dispatch)
    cast_all_kernel<<<11264, 256, 0, stream>>>(x, wq, wk, wv, xb);

    // 2. QKV projection (V stored transposed; Q,K packed [8192,2048])
    gemm_qkv<<<dim3(24, 64, 1), 256, 0, stream>>>(xb, wb, qk, vt);

    // 3. scores_b = Q_b K_b^T -> bf16, triangular tiles only (136/batch)
    gemm_scores<<<dim3(136, 1, 4), 256, 0, stream>>>(qk, sc);

    // 4. single-pass causal softmax -> P bf16
    softmax_kernel<<<8192, 256, 0, stream>>>(sc, P);

    // 5. PV split-K + combine
    gemm_pv<<<dim3(192, 1, 4), 256, 0, stream>>>(P, vt, out, part);
    pv_combine<<<2048, 256, 0, stream>>>(out, part);
}

// Round 8
// 243.843 us; speedup vs baseline: 1.2989x; 1.0493x over previous
//
#include <hip/hip_runtime.h>
#include <hip/hip_bf16.h>

// Causal attention, B=4 S=2048 E=1024 D=1024, fp32 in/out.
// Round 8: fix the round-7 LDS doubling. gemm_qkv inlined gemm_core twice
// (TRANS=0/1), each with its own static __shared__ -> 64 KB/block -> 2
// blocks/CU. Hoist As/Bs into the __global__ wrapper and pass pointers so
// both instantiations share one 32 KB allocation. Rest identical to r7.

typedef unsigned short u16;
typedef __attribute__((ext_vector_type(4))) u16   u16x4;
typedef __attribute__((ext_vector_type(8))) u16   u16x8;
typedef __attribute__((ext_vector_type(8))) short short8;
typedef __attribute__((ext_vector_type(4))) float f32x4;
typedef __attribute__((ext_vector_type(4))) int   i32x4;

__device__ inline u16 f2b(float v) {
    __hip_bfloat16 b = __float2bfloat16(v);
    return *reinterpret_cast<u16*>(&b);
}
__device__ inline float b2f(u16 v) {
    unsigned int u = ((unsigned int)v) << 16;
    return *reinterpret_cast<float*>(&u);
}

template <typename T> __device__ inline void store_elem(T* p, float v);
template <> __device__ inline void store_elem<float>(float* p, float v) { *p = v; }
template <> __device__ inline void store_elem<u16>(u16* p, float v)     { *p = f2b(v); }

// async global->LDS 16B per lane; LDS dest must be wave-uniform base + lane*16
__device__ inline void gload_lds16(const u16* g, u16* l) {
    __builtin_amdgcn_global_load_lds(
        (const __attribute__((address_space(1))) void*)g,
        (__attribute__((address_space(3))) void*)l, 16, 0, 0);
}

// ---------------- merged fp32 -> bf16 cast: [x | wq | wk | wv] -------------
__global__ __launch_bounds__(256) void cast_all_kernel(
    const float* __restrict__ x,  const float* __restrict__ wq,
    const float* __restrict__ wk, const float* __restrict__ wv,
    u16* __restrict__ dst) {
    int q = blockIdx.x * 256 + threadIdx.x;     // quad index, 2883584 total
    const float* src;
    int sidx;
    if (q < 2097152) { src = x; sidx = q * 4; }
    else {
        int qq = q - 2097152;
        int w  = qq >> 18;                      // 262144 quads per weight
        sidx   = (qq & 262143) * 4;
        src    = (w == 0) ? wq : (w == 1) ? wk : wv;
    }
    float4 v = *(const float4*)(src + sidx);
    u16x4 o;
    o.x = f2b(v.x); o.y = f2b(v.y); o.z = f2b(v.z); o.w = f2b(v.w);
    *(u16x4*)(dst + q * 4) = o;
}

// ---------------- BT-GEMM core -----------------------------------------------
#define MT 128
#define NT 128
#define BKH 32
#define HSZ (MT * BKH)   // elems per half buffer = 4096

// As/Bs are caller-provided LDS (2*HSZ each) so multiple instantiations in
// one kernel share a single allocation.
// TRANS=0: C[m][n] = val (OutT). TRANS=1: transposed bf16 store into
// vt[b][d][s] (Cb = vt base, n0 = d base, b/s derived from m).
template <int TRANS, typename OutT>
__device__ __forceinline__ void gemm_core(
    u16* __restrict__ As, u16* __restrict__ Bs,
    const u16* __restrict__ Ab, int lda,
    const u16* __restrict__ Bb, int ldb,
    OutT* __restrict__ Cb, int ldc,
    int m0, int n0, int kbeg, int kend)
{
    const int tid  = threadIdx.x;
    const int lane = tid & 63;
    const int wave = tid >> 6;
    const int quad = lane >> 4;
    const int r16  = lane & 15;
    const int mw   = (wave >> 1) * 64;
    const int nw   = (wave & 1) * 64;

    const int c0 = tid, c1 = tid + 256;
    const int r0 = c0 >> 2, k0 = (c0 & 3) * 8;
    const int r1 = c1 >> 2, k1 = (c1 & 3) * 8;
    const int oa0 = (m0 + r0) * lda + k0;
    const int oa1 = (m0 + r1) * lda + k1;
    const int ob0 = (n0 + r0) * ldb + k0;
    const int ob1 = (n0 + r1) * ldb + k1;

    f32x4 acc[4][4] = {};

    for (int kk = kbeg; kk < kend; kk += 2 * BKH) {
        __syncthreads();
        gload_lds16(Ab + (kk + oa0),        &As[c0 * 8]);
        gload_lds16(Ab + (kk + oa1),        &As[c1 * 8]);
        gload_lds16(Ab + (kk + BKH + oa0),  &As[HSZ + c0 * 8]);
        gload_lds16(Ab + (kk + BKH + oa1),  &As[HSZ + c1 * 8]);
        gload_lds16(Bb + (kk + ob0),        &Bs[c0 * 8]);
        gload_lds16(Bb + (kk + ob1),        &Bs[c1 * 8]);
        gload_lds16(Bb + (kk + BKH + ob0),  &Bs[HSZ + c0 * 8]);
        gload_lds16(Bb + (kk + BKH + ob1),  &Bs[HSZ + c1 * 8]);
        __syncthreads();

#pragma unroll
        for (int h = 0; h < 2; h++) {
            short8 af[4], bf[4];
#pragma unroll
            for (int i = 0; i < 4; i++)
                af[i] = *(const short8*)&As[h * HSZ + (mw + i * 16 + r16) * BKH + quad * 8];
#pragma unroll
            for (int j = 0; j < 4; j++)
                bf[j] = *(const short8*)&Bs[h * HSZ + (nw + j * 16 + r16) * BKH + quad * 8];
#pragma unroll
            for (int i = 0; i < 4; i++)
#pragma unroll
                for (int j = 0; j < 4; j++)
                    acc[i][j] = __builtin_amdgcn_mfma_f32_16x16x32_bf16(af[i], bf[j], acc[i][j], 0, 0, 0);
        }
    }

    // epilogue: C/D layout col=lane&15, row=quad*4+reg
    if (TRANS == 0) {
#pragma unroll
        for (int i = 0; i < 4; i++)
#pragma unroll
            for (int j = 0; j < 4; j++)
#pragma unroll
                for (int r = 0; r < 4; r++) {
                    int m = m0 + mw + i * 16 + quad * 4 + r;
                    int n = n0 + nw + j * 16 + r16;
                    store_elem(&Cb[(long long)m * ldc + n], acc[i][j][r]);
                }
    } else {
#pragma unroll
        for (int i = 0; i < 4; i++)
#pragma unroll
            for (int j = 0; j < 4; j++) {
                int mbase = m0 + mw + i * 16 + quad * 4;      // 4-aligned
                int d     = n0 + nw + j * 16 + r16;
                int b     = mbase >> 11;
                int s     = mbase & 2047;
                u16x4 o;
#pragma unroll
                for (int r = 0; r < 4; r++) o[r] = f2b(acc[i][j][r]);
                *(u16x4*)((u16*)Cb + (((b << 10) + d) * 2048 + s)) = o;
            }
    }
}

// QKV: [8192,1024] x [3072,1024]^T. Blocks x<16 -> qk[8192,2048] (Q|K dense);
// x>=16 -> V, stored transposed into vt[b][d][s].
__global__ __launch_bounds__(256, 4) void gemm_qkv(
    const u16* __restrict__ xb, const u16* __restrict__ wb,
    u16* __restrict__ qk, u16* __restrict__ vt) {
    __shared__ __align__(16) u16 As[2 * HSZ];
    __shared__ __align__(16) u16 Bs[2 * HSZ];
    int bx = blockIdx.x, m0 = blockIdx.y * MT;
    if (bx < 16)
        gemm_core<0, u16>(As, Bs, xb, 1024, wb, 1024, qk, 2048,
                          m0, bx * 128, 0, 1024);
    else
        gemm_core<1, u16>(As, Bs, xb, 1024, wb + 2048 * 1024, 1024, vt, 2048,
                          m0, (bx - 16) * 128, 0, 1024);
}

__global__ __launch_bounds__(256, 4) void gemm_scores(
    const u16* __restrict__ qk, u16* __restrict__ sc) {
    __shared__ __align__(16) u16 As[2 * HSZ];
    __shared__ __align__(16) u16 Bs[2 * HSZ];
    // per batch: Q[2048,1024(ld2048)] x K^T -> sc[2048,2048], lower-tri tiles
    int t = blockIdx.x;
    float ff = sqrtf(8.0f * t + 1.0f);
    int m = (int)((ff - 1.0f) * 0.5f);
    while ((m + 1) * (m + 2) / 2 <= t) m++;
    while (m * (m + 1) / 2 > t) m--;
    int m0 = m * MT;
    int n0 = (t - m * (m + 1) / 2) * NT;
    const u16* Ab = qk + (long long)blockIdx.z * 2048 * 2048;
    const u16* Bb = Ab + 1024;
    u16* Cb = sc + (long long)blockIdx.z * 2048 * 2048;
    gemm_core<0, u16>(As, Bs, Ab, 2048, Bb, 2048, Cb, 2048, m0, n0, 0, 1024);
}

// PV split-K, longest-first schedule: per batch 192 units (see round 5).
__global__ __launch_bounds__(256, 4) void gemm_pv(
    const u16* __restrict__ P, const u16* __restrict__ vt,
    float* __restrict__ out, float* __restrict__ part)
{
    __shared__ __align__(16) u16 As[2 * HSZ];
    __shared__ __align__(16) u16 Bs[2 * HSZ];
    const int bid = blockIdx.x;
    int m, chunk, n;
    if (bid < 80) {                       // K = 1024 class
        int q = bid >> 3; n = bid & 7;
        if (q < 9) { m = 7 + q; chunk = 0; } else { m = 15; chunk = 1; }
    } else {                              // K = s*128, s = 7..1
        int r = bid - 80; int s = 7 - (r >> 4); int t = r & 15;
        n = t & 7;
        if (t < 8) { m = s - 1; chunk = 0; } else { m = s + 7; chunk = 1; }
    }
    const int m0 = m * MT, n0 = n * NT;
    const int kbeg = chunk ? 1024 : 0;
    const int kend = chunk ? (m0 + MT) : min(1024, m0 + MT);
    const int b = blockIdx.z;

    const u16* Ab = P  + (long long)b * 2048 * 2048;
    const u16* Bb = vt + (long long)b * 1024 * 2048;
    float* Cb = (chunk == 0)
        ? out  + (long long)b * 2097152
        : part + (long long)b * 1048576 - 1024LL * 1024;   // rows (m-1024)
    gemm_core<0, float>(As, Bs, Ab, 2048, Bb, 2048, Cb, 1024, m0, n0, kbeg, kend);
}

// combine: out[b][1024+r][c] += part[b][r][c]
__global__ __launch_bounds__(256) void pv_combine(float* __restrict__ out,
                                                  const float* __restrict__ part) {
    long long idx = ((long long)blockIdx.x * 256 + threadIdx.x) * 8;
    long long bb = idx >> 20;
    long long j  = idx & 1048575;
    float* o = out + bb * 2097152 + 1048576 + j;
    const float* p = part + bb * 1048576 + j;
    float4 o0 = *(float4*)o, o1 = *(float4*)(o + 4);
    float4 p0 = *(const float4*)p, p1 = *(const float4*)(p + 4);
    o0.x += p0.x; o0.y += p0.y; o0.z += p0.z; o0.w += p0.w;
    o1.x += p1.x; o1.y += p1.y; o1.z += p1.z; o1.w += p1.w;
    *(float4*)o = o0; *(float4*)(o + 4) = o1;
}

// ---------------- single-pass causal softmax (bf16 in -> bf16 P) -----------
// triangle-trimmed: loads only j<=i, writes only up to the row's 128-aligned
// tile boundary (PV never reads past kend_row = (i & ~127) + 128).
__global__ __launch_bounds__(256) void softmax_kernel(const u16* __restrict__ sc,
                                                      u16* __restrict__ P) {
    const int S = 2048;
    int row = blockIdx.x;            // b*S + i
    int i   = row & (S - 1);
    int n   = i + 1;
    int kendr = (i & ~127) + 128;
    const u16* srow = sc + (long long)row * S;
    u16*       prow = P  + (long long)row * S;

    int j0 = threadIdx.x * 8;
    u16x8 raw = {};
    if (j0 <= i) raw = *(const u16x8*)(srow + j0);
    float v[8];
#pragma unroll
    for (int e = 0; e < 8; e++) v[e] = (j0 + e < n) ? b2f(raw[e]) : -1e30f;

    __shared__ float red[8];
    float lmax = v[0];
#pragma unroll
    for (int e = 1; e < 8; e++) lmax = fmaxf(lmax, v[e]);
    for (int o = 32; o > 0; o >>= 1) lmax = fmaxf(lmax, __shfl_xor(lmax, o, 64));
    int wid = threadIdx.x >> 6;
    if ((threadIdx.x & 63) == 0) red[wid] = lmax;
    __syncthreads();
    float Mx = fmaxf(fmaxf(red[0], red[1]), fmaxf(red[2], red[3]));

    // exp((s-Mx)/32) = exp2((s-Mx) * (1/(32 ln2)))
    const float C = 0.045112384f;
    float ev[8];
    float lsum = 0.f;
#pragma unroll
    for (int e = 0; e < 8; e++) {
        ev[e] = (j0 + e < n) ? exp2f((v[e] - Mx) * C) : 0.f;
        lsum += ev[e];
    }
    for (int o = 32; o > 0; o >>= 1) lsum += __shfl_xor(lsum, o, 64);
    if ((threadIdx.x & 63) == 0) red[4 + wid] = lsum;
    __syncthreads();
    float inv = 1.0f / (red[4] + red[5] + red[6] + red[7]);

    if (j0 < kendr) {
        u16x8 o8;
#pragma unroll
        for (int e = 0; e < 8; e++) o8[e] = f2b(ev[e] * inv);
        *(u16x8*)(prow + j0) = o8;
    }
}

extern "C" void kernel_launch(void* const* d_in, const int* in_sizes, int n_in,
                              void* d_out, int out_size, void* d_ws, size_t ws_size,
                              hipStream_t stream) {
    const float* x  = (const float*)d_in[0];
    const float* wq = (const float*)d_in[1];
    const float* wk = (const float*)d_in[2];
    const float* wv = (const float*)d_in[3];
    float* out = (float*)d_out;

    char* ws = (char*)d_ws;
    // layout: xb 16M | wb 6M | qk 32M | sc 32M | P 32M | vt 16M | part 16M
    u16*   xb   = (u16*)(ws);
    u16*   wb   = (u16*)(ws + 16777216LL);
    u16*   qk   = (u16*)(ws + 23068672LL);
    u16*   sc   = (u16*)(ws + 56623104LL);
    u16*   P    = (u16*)(ws + 90177536LL);
    u16*   vt   = (u16*)(ws + 123731968LL);
    float* part = (float*)(ws + 140509184LL);   // total 157,286,400 bytes

    // 1. casts (x + 3 weights, one dispatch)
    cast_all_kernel<<<11264, 256, 0, stream>>>(x, wq, wk, wv, xb);

    // 2. QKV projection (V stored transposed; Q,K packed [8192,2048])
    gemm_qkv<<<dim3(24, 64, 1), 256, 0, stream>>>(xb, wb, qk, vt);

    // 3. scores_b = Q_b K_b^T -> bf16, triangular tiles only (136/batch)
    gemm_scores<<<dim3(136, 1, 4), 256, 0, stream>>>(qk, sc);

    // 4. single-pass causal softmax -> P bf16
    softmax_kernel<<<8192, 256, 0, stream>>>(sc, P);

    // 5. PV split-K + combine
    gemm_pv<<<dim3(192, 1, 4), 256, 0, stream>>>(P, vt, out, part);
    pv_combine<<<2048, 256, 0, stream>>>(out, part);
}